// Round 18
// baseline (571.518 us; speedup 1.0000x reference)
//
#include <hip/hip_runtime.h>
#include <hip/hip_fp16.h>

typedef _Float16 f16;
typedef unsigned short u16;
typedef f16 f16x2 __attribute__((ext_vector_type(2)));
typedef f16 f16x8 __attribute__((ext_vector_type(8)));
typedef float f32x4 __attribute__((ext_vector_type(4)));

constexpr int N_NODES = 50000;
constexpr int E_EDGES = 800000;
constexpr int NBINS   = 50176;            // 196 * 256
constexpr int NBLK    = 196;

// workspace layout (bytes) -- total 55,995,008 B, UNDER the known-good 59.13 MB
constexpr size_t OFF_DEG   = 0;           // NBINS*4
constexpr size_t OFF_LOCEX = 200704;      // NBINS*4
constexpr size_t OFF_BSUM  = 401408;      // 1024
constexpr size_t OFF_BOFF  = 402432;      // 1024
constexpr size_t OFF_FILL  = 403456;      // NBINS*4
constexpr size_t OFF_SCAT  = 604160;      // N*2*4
constexpr size_t OFF_SROW  = 1004160;     // E*2 (u16)
constexpr size_t OFF_SCOL  = 2604160;     // E*2 (u16)
constexpr size_t OFF_ZSUM  = 4204160;     // N*128*2 (f16, pk atomics; region sized f32 for slack)
constexpr size_t ZSH_BYTES = (size_t)N_NODES * 128 * 2;
constexpr size_t ZS_BYTES  = (size_t)N_NODES * 128 * 4;
constexpr size_t OFF_APRE  = OFF_ZSUM + ZS_BYTES;     // 29,804,160: N*128*2 (f16)
constexpr size_t OFF_BPRE  = OFF_APRE + (size_t)N_NODES * 128 * 2;  // 42,604,160
constexpr size_t OFF_CMB   = OFF_BPRE + (size_t)N_NODES * 128 * 2;  // 55,404,160
constexpr size_t OFF_WX    = OFF_CMB + 65536;
constexpr size_t OFF_BVEC  = OFF_WX + 65536;
constexpr size_t OFF_BX    = OFF_BVEC + 512;
constexpr size_t OFF_WSWZ  = OFF_BX + 512;            // 55,536,256 + 458,752 = 55,995,008

// f32 -> f16 hi/lo split: x ~= hi + lo, |err| <= 2^-22 |x|
__device__ __forceinline__ void split_f(float x, f16& h, f16& l) {
    h = (f16)x;
    l = (f16)(x - (float)h);
}

__device__ __forceinline__ f32x4 mfma3(f16x8 ah, f16x8 al, f16x8 bh, f16x8 bl, f32x4 acc) {
    acc = __builtin_amdgcn_mfma_f32_16x16x32_f16(ah, bh, acc, 0, 0, 0);
    acc = __builtin_amdgcn_mfma_f32_16x16x32_f16(al, bh, acc, 0, 0, 0);
    acc = __builtin_amdgcn_mfma_f32_16x16x32_f16(ah, bl, acc, 0, 0, 0);
    return acc;
}

// packed f16x2 atomic add (native global_atomic_pk_add_f16 on gfx950)
__device__ __forceinline__ void pk_atomic_add(f16* addr, float a0, float a1) {
    __half2 hv = __floats2half2_rn(a0, a1);
    unsafeAtomicAdd((__half2*)addr, hv);
}

// ---- compose: Wcomb = eW2@nW1_bot, Wx = eW2@cW1, bvec = eb2@nW1_bot, bx = eb2@cW1+cb1 ----
__global__ __launch_bounds__(256) void compose_kernel(
    const float* __restrict__ eW2, const float* __restrict__ eb2,
    const float* __restrict__ nW1, const float* __restrict__ cW1,
    const float* __restrict__ cb1,
    float* __restrict__ Wcmb, float* __restrict__ Wx,
    float* __restrict__ bvec, float* __restrict__ bx)
{
    const int gid = blockIdx.x * 256 + threadIdx.x;   // 33024 total
    if (gid < 16384) {
        const int k = gid >> 7, j = gid & 127;
        float s = 0.f;
        for (int t2 = 0; t2 < 128; ++t2) s += eW2[k * 128 + t2] * nW1[(128 + t2) * 128 + j];
        Wcmb[gid] = s;
    } else if (gid < 32768) {
        const int e = gid - 16384;
        const int k = e >> 7, j = e & 127;
        float s = 0.f;
        for (int t2 = 0; t2 < 128; ++t2) s += eW2[k * 128 + t2] * cW1[t2 * 128 + j];
        Wx[e] = s;
    } else if (gid < 32896) {
        const int j = gid - 32768;
        float s = 0.f;
        for (int k = 0; k < 128; ++k) s += eb2[k] * nW1[(128 + k) * 128 + j];
        bvec[j] = s;
    } else if (gid < 33024) {
        const int j = gid - 32896;
        float s = cb1[j];
        for (int k = 0; k < 128; ++k) s += eb2[k] * cW1[k * 128 + j];
        bx[j] = s;
    }
}

// ---- prep: swizzle weights into fragment-order hi/lo f16 planes ----
__global__ __launch_bounds__(256) void prep_kernel(
    const float* __restrict__ eW1, const float* __restrict__ nW1,
    const float* __restrict__ nW2, const float* __restrict__ vW1,
    const float* __restrict__ Wcmb, const float* __restrict__ Wx,
    f16* __restrict__ Wpres, f16* __restrict__ nW1cs,
    f16* __restrict__ nW2s, f16* __restrict__ vW1s, f16* __restrict__ Wxs)
{
    const int gid = blockIdx.x * 256 + threadIdx.x;   // 114688 total
    int K32, e, which; f16* out;
    if (gid < 32768)       { which = 0; out = Wpres; K32 = 4; e = gid; }
    else if (gid < 65536)  { which = 1; out = nW1cs; K32 = 8; e = gid - 32768; }
    else if (gid < 81920)  { which = 2; out = nW2s;  K32 = 4; e = gid - 65536; }
    else if (gid < 98304)  { which = 3; out = vW1s;  K32 = 4; e = gid - 81920; }
    else                   { which = 4; out = Wxs;   K32 = 4; e = gid - 98304; }
    const int per = 512 * K32;
    const int ct = e / per, rem = e % per;
    const int kk = rem >> 9, lane = (rem >> 3) & 63, j = rem & 7;
    const int col = ct * 16 + (lane & 15);
    const int k = kk * 32 + ((lane >> 4) & 3) * 8 + j;
    float v;
    if (which == 0)      v = (col < 128) ? eW1[k * 128 + col] : eW1[(128 + k) * 128 + (col - 128)];
    else if (which == 1) v = (k < 128) ? nW1[k * 128 + col] : Wcmb[(k - 128) * 128 + col];
    else if (which == 2) v = nW2[k * 128 + col];
    else if (which == 3) v = vW1[k * 128 + col];
    else                 v = Wx[k * 128 + col];
    f16 h, l; split_f(v, h, l);
    const int base = ((ct * K32 + kk) * 2) * 512 + lane * 8 + j;
    out[base] = h;
    out[base + 512] = l;
}

// ---- sort pipeline: counting sort of edges by source row ----
__global__ __launch_bounds__(256) void hist_kernel(const int* __restrict__ eidx,
                                                   int* __restrict__ deg) {
    const int e = blockIdx.x * 256 + threadIdx.x;
    if (e < E_EDGES) atomicAdd(&deg[eidx[e]], 1);
}

__global__ __launch_bounds__(256) void scan1_kernel(const int* __restrict__ deg,
                                                    int* __restrict__ locEx,
                                                    int* __restrict__ blockSum) {
    __shared__ int s[256];
    const int t = threadIdx.x;
    const int gid = blockIdx.x * 256 + t;
    const int v = deg[gid];
    s[t] = v;
    __syncthreads();
    for (int off = 1; off < 256; off <<= 1) {
        const int add = (t >= off) ? s[t - off] : 0;
        __syncthreads();
        s[t] += add;
        __syncthreads();
    }
    locEx[gid] = s[t] - v;
    if (t == 255) blockSum[blockIdx.x] = s[255];
}

__global__ __launch_bounds__(256) void scan2_kernel(const int* __restrict__ blockSum,
                                                    int* __restrict__ blockOff) {
    __shared__ int s[256];
    const int t = threadIdx.x;
    const int v = (t < NBLK) ? blockSum[t] : 0;
    s[t] = v;
    __syncthreads();
    for (int off = 1; off < 256; off <<= 1) {
        const int add = (t >= off) ? s[t - off] : 0;
        __syncthreads();
        s[t] += add;
        __syncthreads();
    }
    if (t < NBLK) blockOff[t] = s[t] - v;
}

__global__ __launch_bounds__(256) void scatter_kernel(const int* __restrict__ eidx,
        const int* __restrict__ locEx, const int* __restrict__ blockOff,
        int* __restrict__ fill, u16* __restrict__ srow, u16* __restrict__ scol) {
    const int e = blockIdx.x * 256 + threadIdx.x;
    if (e >= E_EDGES) return;
    const int r = eidx[e], c = eidx[E_EDGES + e];
    const int pos = blockOff[r >> 8] + locEx[r] + atomicAdd(&fill[r], 1);
    srow[pos] = (u16)r;
    scol[pos] = (u16)c;
}

// staging helper: split 8 f32 into hi/lo octet pair at dst
__device__ __forceinline__ void stage8(const float* src, f16* dst) {
    const float4 f0 = *(const float4*)src;
    const float4 f1 = *(const float4*)(src + 4);
    const float xs[8] = {f0.x, f0.y, f0.z, f0.w, f1.x, f1.y, f1.z, f1.w};
    f16x8 vh, vl;
#pragma unroll
    for (int i = 0; i < 8; ++i) { f16 hh, ll; split_f(xs[i], hh, ll); vh[i] = hh; vl[i] = ll; }
    *(f16x8*)dst = vh;
    *(f16x8*)(dst + 8) = vl;
}

// ---- pre_embed (layer 1): embed fused in. Computes h = h_in@embW + embb inline
// (h_in 3.2MB + embW 8KB instead of re-reading 25.6MB hcur), writes hcur for
// node_core, stages to smA, then pre-GEMM -> Apre/Bpre. Deletes embed_kernel. ----
__global__ __launch_bounds__(256, 4) void pre_embed_kernel(
    const float* __restrict__ h_in, const float* __restrict__ embW,
    const float* __restrict__ embb, float* __restrict__ hcur,
    const f16* __restrict__ Wpres, const float* __restrict__ eb1,
    f16* __restrict__ Apre, f16* __restrict__ Bpre)
{
    constexpr int S = 264;
    __shared__ f16 smA[64 * S];
    const int t = threadIdx.x;
    const int base = blockIdx.x * 64;
    const int lane = t & 63, w = t >> 6, qq = lane >> 4, nn = lane & 15;
    const int segc = t & 15;                 // seg invariant across staging iters
    const float b0 = embb[segc * 8 + 0], b1e = embb[segc * 8 + 1];
    const float b2e = embb[segc * 8 + 2], b3 = embb[segc * 8 + 3];
    const float b4 = embb[segc * 8 + 4], b5 = embb[segc * 8 + 5];
    const float b6 = embb[segc * 8 + 6], b7 = embb[segc * 8 + 7];

#pragma unroll
    for (int it = 0; it < 4; ++it) {
        const int el = it * 16 + (t >> 4);
        const int node = base + el;
        f16* dst = &smA[el * S + segc * 16];
        if (node < N_NODES) {
            const float4 hi0 = *(const float4*)(h_in + (size_t)node * 16);
            const float4 hi1 = *(const float4*)(h_in + (size_t)node * 16 + 4);
            const float4 hi2 = *(const float4*)(h_in + (size_t)node * 16 + 8);
            const float4 hi3 = *(const float4*)(h_in + (size_t)node * 16 + 12);
            const float hv[16] = {hi0.x, hi0.y, hi0.z, hi0.w, hi1.x, hi1.y, hi1.z, hi1.w,
                                  hi2.x, hi2.y, hi2.z, hi2.w, hi3.x, hi3.y, hi3.z, hi3.w};
            float s[8] = {b0, b1e, b2e, b3, b4, b5, b6, b7};
#pragma unroll
            for (int p = 0; p < 16; ++p) {
                const float4 w0 = *(const float4*)(embW + p * 128 + segc * 8);
                const float4 w1 = *(const float4*)(embW + p * 128 + segc * 8 + 4);
                s[0] += hv[p] * w0.x; s[1] += hv[p] * w0.y;
                s[2] += hv[p] * w0.z; s[3] += hv[p] * w0.w;
                s[4] += hv[p] * w1.x; s[5] += hv[p] * w1.y;
                s[6] += hv[p] * w1.z; s[7] += hv[p] * w1.w;
            }
            float4 o0; o0.x = s[0]; o0.y = s[1]; o0.z = s[2]; o0.w = s[3];
            float4 o1; o1.x = s[4]; o1.y = s[5]; o1.z = s[6]; o1.w = s[7];
            float* hp = hcur + (size_t)node * 128 + segc * 8;
            *(float4*)hp = o0;
            *(float4*)(hp + 4) = o1;
            f16x8 vh, vl;
#pragma unroll
            for (int i = 0; i < 8; ++i) { f16 hh, ll; split_f(s[i], hh, ll); vh[i] = hh; vl[i] = ll; }
            *(f16x8*)dst = vh;
            *(f16x8*)(dst + 8) = vl;
        } else {
            *(f16x8*)dst = (f16x8)(f16)0.f;
            *(f16x8*)(dst + 8) = (f16x8)(f16)0.f;
        }
    }
    __syncthreads();

#pragma unroll
    for (int half = 0; half < 2; ++half) {
        f32x4 acc[4][2] = {};
        for (int kk = 0; kk < 4; ++kk) {
            f16x8 Ah[4], Al[4];
#pragma unroll
            for (int rt = 0; rt < 4; ++rt) {
                const f16* ap = &smA[(rt * 16 + nn) * S + (kk * 4 + qq) * 16];
                Ah[rt] = *(const f16x8*)ap;
                Al[rt] = *(const f16x8*)(ap + 8);
            }
#pragma unroll
            for (int c = 0; c < 2; ++c) {
                const int ct = w * 4 + half * 2 + c;
                const f16* bp = Wpres + (size_t)((ct * 4 + kk) * 2) * 512 + lane * 8;
                const f16x8 Bh = *(const f16x8*)bp;
                const f16x8 Bl = *(const f16x8*)(bp + 512);
#pragma unroll
                for (int rt = 0; rt < 4; ++rt)
                    acc[rt][c] = mfma3(Ah[rt], Al[rt], Bh, Bl, acc[rt][c]);
            }
        }
#pragma unroll
        for (int c = 0; c < 2; ++c) {
            const int col = w * 64 + half * 32 + c * 16 + nn;   // 0..255
#pragma unroll
            for (int rt = 0; rt < 4; ++rt) {
#pragma unroll
                for (int r = 0; r < 4; ++r) {
                    const int el = rt * 16 + qq * 4 + r;
                    const int node = base + el;
                    if (node < N_NODES) {
                        const float v = acc[rt][c][r];
                        if (col < 128) Apre[(size_t)node * 128 + col] = (f16)(v + eb1[col]);
                        else           Bpre[(size_t)node * 128 + (col - 128)] = (f16)v;
                    }
                }
            }
        }
    }
}

// ---- edge_z (layer 1): z tile in LDS; 4-deep batched gather (8 loads in flight);
// col-pair merge with wave-uniform flush (pk atomics) ----
__global__ __launch_bounds__(256, 8) void edge_z_kernel(
    const u16* __restrict__ srow, const u16* __restrict__ scol,
    const float* __restrict__ x,
    const f16* __restrict__ Apre, const f16* __restrict__ Bpre,
    const float* __restrict__ wlast,
    f16* __restrict__ zsumh)
{
    constexpr int S2 = 136;
    __shared__ f16 smZ[64 * S2];      // 17408 B, row-major [edge][col]
    __shared__ int smRow[64], smCol[64];
    __shared__ float smRd[64];
    const int t = threadIdx.x;
    const int base = blockIdx.x * 64;
    if (t < 64) {
        const int e = base + t;
        const int r = (int)srow[e], c = (int)scol[e];
        smRow[t] = r; smCol[t] = c;
        const float dx = x[2 * r] - x[2 * c];
        const float dy = x[2 * r + 1] - x[2 * c + 1];
        smRd[t] = dx * dx + dy * dy;
    }
    __syncthreads();

    const int seg = t & 15, el0 = t >> 4;
    const float4 w0 = *(const float4*)(wlast + seg * 8);
    const float4 w1 = *(const float4*)(wlast + seg * 8 + 4);
    const float wl[8] = {w0.x, w0.y, w0.z, w0.w, w1.x, w1.y, w1.z, w1.w};
    // batched gather: all 8 loads issued before any consumption (MLP=8)
    f16x8 AV[4], BV[4];
#pragma unroll
    for (int it = 0; it < 4; ++it) {
        const int el = it * 16 + el0;
        AV[it] = *(const f16x8*)(Apre + (size_t)smRow[el] * 128 + seg * 8);
        BV[it] = *(const f16x8*)(Bpre + (size_t)smCol[el] * 128 + seg * 8);
    }
#pragma unroll
    for (int it = 0; it < 4; ++it) {
        const int el = it * 16 + el0;
        const float rd = smRd[el];
        f16x8 vz;
#pragma unroll
        for (int i = 0; i < 8; ++i)
            vz[i] = (f16)fmaxf((float)AV[it][i] + (float)BV[it][i] + rd * wl[i], 0.f);
        *(f16x8*)&smZ[el * S2 + seg * 8] = vz;
    }
    __syncthreads();

    const int p = t & 63, g = t >> 6;
    float a0 = 0.f, a1 = 0.f;
    int prev = smRow[g * 16];
#pragma unroll
    for (int e = g * 16; e < g * 16 + 16; ++e) {
        const int rw = smRow[e];
        if (rw != prev) {
            pk_atomic_add(&zsumh[(size_t)prev * 128 + 2 * p], a0, a1);
            a0 = a1 = 0.f; prev = rw;
        }
        const f16x2 v = *(const f16x2*)&smZ[e * S2 + 2 * p];
        a0 += (float)v[0]; a1 += (float)v[1];
    }
    pk_atomic_add(&zsumh[(size_t)prev * 128 + 2 * p], a0, a1);
}

// ---- edge_coord (layer 2): batched-gather z tile + merge + coord MFMA (LB 8) ----
__global__ __launch_bounds__(256, 8) void edge_coord_kernel(
    const u16* __restrict__ srow, const u16* __restrict__ scol,
    const float* __restrict__ x,
    const f16* __restrict__ Apre, const f16* __restrict__ Bpre,
    const float* __restrict__ wlast,
    const f16* __restrict__ Wxs, const float* __restrict__ bx,
    const float* __restrict__ cW2, const float* __restrict__ cb2,
    f16* __restrict__ zsumh, float* __restrict__ scat)
{
    constexpr int S2 = 136;
    __shared__ f16 smZ[64 * S2];      // 17408 B
    __shared__ int smRow[64], smCol[64];
    __shared__ float smRd[64], smP2x[64], smP2y[64];
    __shared__ float smPart[4][64];

    const int t = threadIdx.x;
    const int base = blockIdx.x * 64;
    const int lane = t & 63, w = t >> 6, qq = lane >> 4, nn = lane & 15;

    if (t < 64) {
        const int e = base + t;
        const int r = (int)srow[e], c = (int)scol[e];
        smRow[t] = r; smCol[t] = c;
        const float dx = x[2 * r] - x[2 * c];
        const float dy = x[2 * r + 1] - x[2 * c + 1];
        smRd[t] = dx * dx + dy * dy;
        smP2x[t] = dx * dx - dy * dy;     // rel_dist*cos(2θ) exactly
        smP2y[t] = 2.0f * dx * dy;        // rel_dist*sin(2θ) exactly
    }
    __syncthreads();

    {
        const int seg = t & 15, el0 = t >> 4;
        const float4 w0 = *(const float4*)(wlast + seg * 8);
        const float4 w1 = *(const float4*)(wlast + seg * 8 + 4);
        const float wl[8] = {w0.x, w0.y, w0.z, w0.w, w1.x, w1.y, w1.z, w1.w};
        f16x8 AV[4], BV[4];
#pragma unroll
        for (int it = 0; it < 4; ++it) {
            const int el = it * 16 + el0;
            AV[it] = *(const f16x8*)(Apre + (size_t)smRow[el] * 128 + seg * 8);
            BV[it] = *(const f16x8*)(Bpre + (size_t)smCol[el] * 128 + seg * 8);
        }
#pragma unroll
        for (int it = 0; it < 4; ++it) {
            const int el = it * 16 + el0;
            const float rd = smRd[el];
            f16x8 vz;
#pragma unroll
            for (int i = 0; i < 8; ++i)
                vz[i] = (f16)fmaxf((float)AV[it][i] + (float)BV[it][i] + rd * wl[i], 0.f);
            *(f16x8*)&smZ[el * S2 + seg * 8] = vz;
        }
    }
    __syncthreads();

    {
        const int p = t & 63, g = t >> 6;
        float a0 = 0.f, a1 = 0.f;
        int prev = smRow[g * 16];
#pragma unroll
        for (int e = g * 16; e < g * 16 + 16; ++e) {
            const int rw = smRow[e];
            if (rw != prev) {
                pk_atomic_add(&zsumh[(size_t)prev * 128 + 2 * p], a0, a1);
                a0 = a1 = 0.f; prev = rw;
            }
            const f16x2 v = *(const f16x2*)&smZ[e * S2 + 2 * p];
            a0 += (float)v[0]; a1 += (float)v[1];
        }
        pk_atomic_add(&zsumh[(size_t)prev * 128 + 2 * p], a0, a1);
    }

    // ---- coord: co = relu(z @ Wx + bx) @ cW2 + cb2 ; scatter rel_pos2*co ----
    f32x4 acc3[4][2] = {};
    for (int kk = 0; kk < 4; ++kk) {
        f16x8 A[4];
#pragma unroll
        for (int rt = 0; rt < 4; ++rt)
            A[rt] = *(const f16x8*)&smZ[(rt * 16 + nn) * S2 + (kk * 4 + qq) * 8];
#pragma unroll
        for (int c = 0; c < 2; ++c) {
            const int ct = w * 2 + c;
            const f16x8 Bh = *(const f16x8*)(Wxs + (size_t)((ct * 4 + kk) * 2) * 512 + lane * 8);
#pragma unroll
            for (int rt = 0; rt < 4; ++rt)
                acc3[rt][c] = __builtin_amdgcn_mfma_f32_16x16x32_f16(A[rt], Bh, acc3[rt][c], 0, 0, 0);
        }
    }
    float p3[4][4];
#pragma unroll
    for (int rt = 0; rt < 4; ++rt)
#pragma unroll
        for (int r = 0; r < 4; ++r) p3[rt][r] = 0.f;
#pragma unroll
    for (int c = 0; c < 2; ++c) {
        const int col = w * 32 + c * 16 + nn;
        const float c1 = bx[col];
        const float w2 = cW2[col];
#pragma unroll
        for (int rt = 0; rt < 4; ++rt)
#pragma unroll
            for (int r = 0; r < 4; ++r)
                p3[rt][r] += fmaxf(acc3[rt][c][r] + c1, 0.f) * w2;
    }
#pragma unroll
    for (int off = 1; off < 16; off <<= 1)
#pragma unroll
        for (int rt = 0; rt < 4; ++rt)
#pragma unroll
            for (int r = 0; r < 4; ++r) p3[rt][r] += __shfl_xor(p3[rt][r], off);
    if (nn == 0) {
#pragma unroll
        for (int rt = 0; rt < 4; ++rt)
#pragma unroll
            for (int r = 0; r < 4; ++r)
                smPart[w][rt * 16 + qq * 4 + r] = p3[rt][r];
    }
    __syncthreads();
    if (t < 64) {
        const float co = smPart[0][t] + smPart[1][t] + smPart[2][t] + smPart[3][t] + cb2[0];
        const int rw = smRow[t];
        atomicAdd(&scat[2 * rw],     smP2x[t] * co);
        atomicAdd(&scat[2 * rw + 1], smP2y[t] * co);
    }
}

// ---- node core: computes h_new, writes h, leaves h_new staged in smA (fragment
// layout, hi/lo split). Shared by both fused kernels. ----
__device__ __forceinline__ void node_core(
    float* __restrict__ h, f16* __restrict__ zsumh,
    const int* __restrict__ deg,
    const f16* __restrict__ nW1cs, const float* __restrict__ nb1,
    const float* __restrict__ bvec,
    const f16* __restrict__ nW2s, const float* __restrict__ nb2,
    f16* smA, float* smDeg, int t, int base)
{
    constexpr int S = 264;
    const int lane = t & 63, w = t >> 6, qq = lane >> 4, nn = lane & 15;

    if (t < 64) smDeg[t] = (float)deg[base + t];   // base+63 <= 50047 < NBINS, safe

    f32x4 acc1[4][2] = {};
    for (int chunk = 0; chunk < 2; ++chunk) {
        if (chunk) __syncthreads();
#pragma unroll
        for (int it = 0; it < 4; ++it) {
            const int idx = it * 256 + t;
            const int el = idx >> 4, seg = idx & 15;
            const int node = base + el;
            f16* dst = &smA[el * S + seg * 16];
            if (node < N_NODES) {
                if (chunk == 0) {
                    stage8(h + (size_t)node * 128 + seg * 8, dst);
                } else {
                    f16* src = zsumh + (size_t)node * 128 + seg * 8;
                    const f16x8 v = *(const f16x8*)src;
                    *(f16x8*)dst = v;                       // hi plane = f16 value
                    *(f16x8*)(dst + 8) = (f16x8)(f16)0.f;   // lo plane = 0
                    *(f16x8*)src = (f16x8)(f16)0.f;         // zero zsumh in place
                }
            } else {
                *(f16x8*)dst = (f16x8)(f16)0.f;
                *(f16x8*)(dst + 8) = (f16x8)(f16)0.f;
            }
        }
        __syncthreads();
        for (int kk = 0; kk < 4; ++kk) {
            f16x8 Ah[4], Al[4];
#pragma unroll
            for (int rt = 0; rt < 4; ++rt) {
                const f16* ap = &smA[(rt * 16 + nn) * S + (kk * 4 + qq) * 16];
                Ah[rt] = *(const f16x8*)ap;
                Al[rt] = *(const f16x8*)(ap + 8);
            }
            const int kkg = chunk * 4 + kk;
#pragma unroll
            for (int c = 0; c < 2; ++c) {
                const int ct = w * 2 + c;
                const f16* bp = nW1cs + (size_t)((ct * 8 + kkg) * 2) * 512 + lane * 8;
                const f16x8 Bh = *(const f16x8*)bp;
                const f16x8 Bl = *(const f16x8*)(bp + 512);
#pragma unroll
                for (int rt = 0; rt < 4; ++rt)
                    acc1[rt][c] = mfma3(Ah[rt], Al[rt], Bh, Bl, acc1[rt][c]);
            }
        }
    }
    __syncthreads();
#pragma unroll
    for (int c = 0; c < 2; ++c) {
        const int col = w * 32 + c * 16 + nn;
        const float b1 = nb1[col];
        const float bv = bvec[col];
#pragma unroll
        for (int rt = 0; rt < 4; ++rt) {
#pragma unroll
            for (int r = 0; r < 4; ++r) {
                const int el = rt * 16 + qq * 4 + r;
                const float z = fmaxf(acc1[rt][c][r] + b1 + smDeg[el] * bv, 0.f);
                f16 zh, zl; split_f(z, zh, zl);
                f16* zp = &smA[el * S + (col >> 3) * 16 + (col & 7)];
                zp[0] = zh; zp[8] = zl;
            }
        }
    }
    __syncthreads();

    f32x4 acc2[4][2] = {};
    for (int kk = 0; kk < 4; ++kk) {
        f16x8 Ah[4], Al[4];
#pragma unroll
        for (int rt = 0; rt < 4; ++rt) {
            const f16* ap = &smA[(rt * 16 + nn) * S + (kk * 4 + qq) * 16];
            Ah[rt] = *(const f16x8*)ap;
            Al[rt] = *(const f16x8*)(ap + 8);
        }
#pragma unroll
        for (int c = 0; c < 2; ++c) {
            const int ct = w * 2 + c;
            const f16* bp = nW2s + (size_t)((ct * 4 + kk) * 2) * 512 + lane * 8;
            const f16x8 Bh = *(const f16x8*)bp;
            const f16x8 Bl = *(const f16x8*)(bp + 512);
#pragma unroll
            for (int rt = 0; rt < 4; ++rt)
                acc2[rt][c] = mfma3(Ah[rt], Al[rt], Bh, Bl, acc2[rt][c]);
        }
    }
    __syncthreads();   // smA z reads done -> overwrite with h_new
#pragma unroll
    for (int c = 0; c < 2; ++c) {
        const int col = w * 32 + c * 16 + nn;
        const float b2 = nb2[col];
#pragma unroll
        for (int rt = 0; rt < 4; ++rt) {
#pragma unroll
            for (int r = 0; r < 4; ++r) {
                const int el = rt * 16 + qq * 4 + r;
                const int node = base + el;
                if (node < N_NODES) {
                    const size_t ix = (size_t)node * 128 + col;
                    const float hn = h[ix] + acc2[rt][c][r] + b2;
                    h[ix] = hn;
                    f16 hh, hl; split_f(hn, hh, hl);
                    f16* hp = &smA[el * S + (col >> 3) * 16 + (col & 7)];
                    hp[0] = hh; hp[8] = hl;
                }
                // node >= N: stale smA rows harmless (outputs guarded by node<N)
            }
        }
    }
    __syncthreads();   // h_new staged for the fused consumer GEMM
}

// ---- node_pre (layer 1): node update fused with pre-GEMM for layer 2 ----
__global__ __launch_bounds__(256, 4) void node_pre_kernel(
    float* __restrict__ h, f16* __restrict__ zsumh,
    const int* __restrict__ deg,
    const f16* __restrict__ nW1cs, const float* __restrict__ nb1,
    const float* __restrict__ bvec,
    const f16* __restrict__ nW2s, const float* __restrict__ nb2,
    const f16* __restrict__ Wpres, const float* __restrict__ eb1,
    f16* __restrict__ Apre, f16* __restrict__ Bpre)
{
    constexpr int S = 264;
    __shared__ f16 smA[64 * S];
    __shared__ float smDeg[64];
    const int t = threadIdx.x;
    const int base = blockIdx.x * 64;
    const int lane = t & 63, w = t >> 6, qq = lane >> 4, nn = lane & 15;

    node_core(h, zsumh, deg, nW1cs, nb1, bvec, nW2s, nb2, smA, smDeg, t, base);

    // pre-GEMM on staged h_new: Apre = h@eW1_top + eb1, Bpre = h@eW1_bot
#pragma unroll
    for (int half = 0; half < 2; ++half) {
        f32x4 acc[4][2] = {};
        for (int kk = 0; kk < 4; ++kk) {
            f16x8 Ah[4], Al[4];
#pragma unroll
            for (int rt = 0; rt < 4; ++rt) {
                const f16* ap = &smA[(rt * 16 + nn) * S + (kk * 4 + qq) * 16];
                Ah[rt] = *(const f16x8*)ap;
                Al[rt] = *(const f16x8*)(ap + 8);
            }
#pragma unroll
            for (int c = 0; c < 2; ++c) {
                const int ct = w * 4 + half * 2 + c;
                const f16* bp = Wpres + (size_t)((ct * 4 + kk) * 2) * 512 + lane * 8;
                const f16x8 Bh = *(const f16x8*)bp;
                const f16x8 Bl = *(const f16x8*)(bp + 512);
#pragma unroll
                for (int rt = 0; rt < 4; ++rt)
                    acc[rt][c] = mfma3(Ah[rt], Al[rt], Bh, Bl, acc[rt][c]);
            }
        }
#pragma unroll
        for (int c = 0; c < 2; ++c) {
            const int col = w * 64 + half * 32 + c * 16 + nn;   // 0..255
#pragma unroll
            for (int rt = 0; rt < 4; ++rt) {
#pragma unroll
                for (int r = 0; r < 4; ++r) {
                    const int el = rt * 16 + qq * 4 + r;
                    const int node = base + el;
                    if (node < N_NODES) {
                        const float v = acc[rt][c][r];
                        if (col < 128) Apre[(size_t)node * 128 + col] = (f16)(v + eb1[col]);
                        else           Bpre[(size_t)node * 128 + (col - 128)] = (f16)v;
                    }
                }
            }
        }
    }
}

// ---- node_final (layer 2): node update fused with v-MLP + normalize + x copy ----
__global__ __launch_bounds__(256, 4) void node_final_kernel(
    float* __restrict__ h, f16* __restrict__ zsumh,
    const int* __restrict__ deg,
    const f16* __restrict__ nW1cs, const float* __restrict__ nb1,
    const float* __restrict__ bvec,
    const f16* __restrict__ nW2s, const float* __restrict__ nb2,
    const f16* __restrict__ vW1s, const float* __restrict__ vb1,
    const float* __restrict__ vW2, const float* __restrict__ vb2,
    const float* __restrict__ scat, const float* __restrict__ x,
    float* __restrict__ out)
{
    constexpr int S = 264;
    __shared__ f16 smA[64 * S];
    __shared__ float smDeg[64];
    const int t = threadIdx.x;
    const int base = blockIdx.x * 64;
    const int lane = t & 63, w = t >> 6, qq = lane >> 4, nn = lane & 15;

    node_core(h, zsumh, deg, nW1cs, nb1, bvec, nW2s, nb2, smA, smDeg, t, base);

    // v-GEMM on staged h_new: z = relu(h@vW1 + vb1) -> smA
    f32x4 acc1[4][2] = {};
    for (int kk = 0; kk < 4; ++kk) {
        f16x8 Ah[4], Al[4];
#pragma unroll
        for (int rt = 0; rt < 4; ++rt) {
            const f16* ap = &smA[(rt * 16 + nn) * S + (kk * 4 + qq) * 16];
            Ah[rt] = *(const f16x8*)ap;
            Al[rt] = *(const f16x8*)(ap + 8);
        }
#pragma unroll
        for (int c = 0; c < 2; ++c) {
            const int ct = w * 2 + c;
            const f16* bp = vW1s + (size_t)((ct * 4 + kk) * 2) * 512 + lane * 8;
            const f16x8 Bh = *(const f16x8*)bp;
            const f16x8 Bl = *(const f16x8*)(bp + 512);
#pragma unroll
            for (int rt = 0; rt < 4; ++rt)
                acc1[rt][c] = mfma3(Ah[rt], Al[rt], Bh, Bl, acc1[rt][c]);
        }
    }
    __syncthreads();
#pragma unroll
    for (int c = 0; c < 2; ++c) {
        const int col = w * 32 + c * 16 + nn;
        const float b1 = vb1[col];
#pragma unroll
        for (int rt = 0; rt < 4; ++rt) {
#pragma unroll
            for (int r = 0; r < 4; ++r) {
                const int el = rt * 16 + qq * 4 + r;
                const float z = fmaxf(acc1[rt][c][r] + b1, 0.f);
                f16 zh, zl; split_f(z, zh, zl);
                f16* zp = &smA[el * S + (col >> 3) * 16 + (col & 7)];
                zp[0] = zh; zp[8] = zl;
            }
        }
    }
    __syncthreads();

    float* out_x = out + (size_t)N_NODES * 128;
    float* out_v = out_x + (size_t)N_NODES * 2;
    if (t < 128) {
        const int node = base + (t >> 1);
        if (node < N_NODES) out_x[node * 2 + (t & 1)] = x[node * 2 + (t & 1)];
    }
    if (t < 128) {
        const int rl = t >> 1, comp = t & 1;
        const int node = base + rl;
        float s = 0.f;
        if (node < N_NODES) {
            s = vb2[comp];
            for (int k = 0; k < 128; ++k) {
                const f16* zp = &smA[rl * S + (k >> 3) * 16 + (k & 7)];
                const float z = (float)zp[0] + (float)zp[8];
                s += z * vW2[k * 2 + comp];
            }
            const float dn = fmaxf((float)smDeg[rl], 1.0f);
            s += scat[node * 2 + comp] / dn;
        }
        const float other = __shfl_xor(s, 1);
        if (node < N_NODES) {
            const float nrm = sqrtf(s * s + other * other);
            out_v[node * 2 + comp] = s / fmaxf(nrm, 1e-12f);
        }
    }
}

extern "C" void kernel_launch(void* const* d_in, const int* in_sizes, int n_in,
                              void* d_out, int out_size, void* d_ws, size_t ws_size,
                              hipStream_t stream) {
    const float* h_in = (const float*)d_in[0];
    const float* x    = (const float*)d_in[1];
    const int*   eidx = (const int*)d_in[2];
    const float* embW = (const float*)d_in[3];
    const float* embb = (const float*)d_in[4];
    const float* eW1  = (const float*)d_in[5];
    const float* eb1  = (const float*)d_in[6];
    const float* eW2  = (const float*)d_in[7];
    const float* eb2  = (const float*)d_in[8];
    const float* nW1  = (const float*)d_in[9];
    const float* nb1  = (const float*)d_in[10];
    const float* nW2  = (const float*)d_in[11];
    const float* nb2  = (const float*)d_in[12];
    const float* vW1  = (const float*)d_in[13];
    const float* vb1  = (const float*)d_in[14];
    const float* vW2  = (const float*)d_in[15];
    const float* vb2  = (const float*)d_in[16];
    const float* cW1  = (const float*)d_in[17];
    const float* cb1  = (const float*)d_in[18];
    const float* cW2  = (const float*)d_in[19];
    const float* cb2  = (const float*)d_in[20];

    char* ws = (char*)d_ws;
    int* deg    = (int*)(ws + OFF_DEG);
    int* locEx  = (int*)(ws + OFF_LOCEX);
    int* bsum   = (int*)(ws + OFF_BSUM);
    int* boff   = (int*)(ws + OFF_BOFF);
    int* fill   = (int*)(ws + OFF_FILL);
    float* scat = (float*)(ws + OFF_SCAT);
    u16* srow   = (u16*)(ws + OFF_SROW);
    u16* scol   = (u16*)(ws + OFF_SCOL);
    f16* zsumh  = (f16*)(ws + OFF_ZSUM);
    f16* Apre   = (f16*)(ws + OFF_APRE);
    f16* Bpre   = (f16*)(ws + OFF_BPRE);
    float* Wcmb = (float*)(ws + OFF_CMB);
    float* Wx   = (float*)(ws + OFF_WX);
    float* bvec = (float*)(ws + OFF_BVEC);
    float* bx   = (float*)(ws + OFF_BX);
    f16* Wpres  = (f16*)(ws + OFF_WSWZ);
    f16* nW1cs  = Wpres + 65536;
    f16* nW2s   = nW1cs + 65536;
    f16* vW1s   = nW2s + 32768;
    f16* Wxs    = vW1s + 32768;

    // h lives in d_out's h-region: final copy is free
    float* hcur = (float*)d_out;

    // zero deg/locEx/bsum/boff/fill/scat (1 MB) + zsumh (12.8 MB; node kernels
    // re-zero zsumh in-place every call thereafter)
    hipMemsetAsync(ws, 0, OFF_SROW, stream);
    hipMemsetAsync(zsumh, 0, ZSH_BYTES, stream);

    compose_kernel<<<129, 256, 0, stream>>>(eW2, eb2, nW1, cW1, cb1, Wcmb, Wx, bvec, bx);
    prep_kernel<<<448, 256, 0, stream>>>(eW1, nW1, nW2, vW1, Wcmb, Wx,
                                         Wpres, nW1cs, nW2s, vW1s, Wxs);
    hist_kernel<<<(E_EDGES + 255) / 256, 256, 0, stream>>>(eidx, deg);
    scan1_kernel<<<NBLK, 256, 0, stream>>>(deg, locEx, bsum);
    scan2_kernel<<<1, 256, 0, stream>>>(bsum, boff);
    scatter_kernel<<<(E_EDGES + 255) / 256, 256, 0, stream>>>(eidx, locEx, boff,
                                                              fill, srow, scol);

    const float* wlast = eW1 + 256 * 128;   // rel_dist row of eW1

    // layer 1 (embed fused into pre: reads h_in 3.2MB instead of hcur 25.6MB,
    // writes hcur for node_core, deletes the embed dispatch)
    pre_embed_kernel<<<(N_NODES + 63) / 64, 256, 0, stream>>>(h_in, embW, embb, hcur,
        Wpres, eb1, Apre, Bpre);
    edge_z_kernel<<<E_EDGES / 64, 256, 0, stream>>>(srow, scol, x, Apre, Bpre, wlast, zsumh);
    node_pre_kernel<<<(N_NODES + 63) / 64, 256, 0, stream>>>(hcur, zsumh, deg,
        nW1cs, nb1, bvec, nW2s, nb2, Wpres, eb1, Apre, Bpre);

    // layer 2 (with coord + scatter); zsumh zeroed in-place by node_pre
    edge_coord_kernel<<<E_EDGES / 64, 256, 0, stream>>>(srow, scol, x, Apre, Bpre, wlast,
        Wxs, bx, cW2, cb2, zsumh, scat);
    node_final_kernel<<<(N_NODES + 63) / 64, 256, 0, stream>>>(hcur, zsumh, deg,
        nW1cs, nb1, bvec, nW2s, nb2, vW1s, vb1, vW2, vb2, scat, x, (float*)d_out);
}

// Round 19
// 561.696 us; speedup vs baseline: 1.0175x; 1.0175x over previous
//
#include <hip/hip_runtime.h>
#include <hip/hip_fp16.h>

typedef _Float16 f16;
typedef unsigned short u16;
typedef f16 f16x2 __attribute__((ext_vector_type(2)));
typedef f16 f16x8 __attribute__((ext_vector_type(8)));
typedef float f32x4 __attribute__((ext_vector_type(4)));

constexpr int N_NODES = 50000;
constexpr int E_EDGES = 800000;
constexpr int NBINS   = 50176;            // 196 * 256
constexpr int NBLK    = 196;

// workspace layout (bytes) -- total 55,995,008 B, UNDER the known-good 59.13 MB
constexpr size_t OFF_DEG   = 0;           // NBINS*4
constexpr size_t OFF_LOCEX = 200704;      // NBINS*4
constexpr size_t OFF_BSUM  = 401408;      // 1024
constexpr size_t OFF_BOFF  = 402432;      // 1024
constexpr size_t OFF_FILL  = 403456;      // NBINS*4
constexpr size_t OFF_SCAT  = 604160;      // N*2*4
constexpr size_t OFF_SROW  = 1004160;     // E*2 (u16)
constexpr size_t OFF_SCOL  = 2604160;     // E*2 (u16)
constexpr size_t OFF_ZSUM  = 4204160;     // N*128*2 (f16, pk atomics; region sized f32 for slack)
constexpr size_t ZSH_BYTES = (size_t)N_NODES * 128 * 2;
constexpr size_t ZS_BYTES  = (size_t)N_NODES * 128 * 4;
constexpr size_t OFF_APRE  = OFF_ZSUM + ZS_BYTES;     // 29,804,160: N*128*2 (f16)
constexpr size_t OFF_BPRE  = OFF_APRE + (size_t)N_NODES * 128 * 2;  // 42,604,160
constexpr size_t OFF_CMB   = OFF_BPRE + (size_t)N_NODES * 128 * 2;  // 55,404,160
constexpr size_t OFF_WX    = OFF_CMB + 65536;
constexpr size_t OFF_BVEC  = OFF_WX + 65536;
constexpr size_t OFF_BX    = OFF_BVEC + 512;
constexpr size_t OFF_WSWZ  = OFF_BX + 512;            // 55,536,256 + 458,752 = 55,995,008

// f32 -> f16 hi/lo split: x ~= hi + lo, |err| <= 2^-22 |x|
__device__ __forceinline__ void split_f(float x, f16& h, f16& l) {
    h = (f16)x;
    l = (f16)(x - (float)h);
}

__device__ __forceinline__ f32x4 mfma3(f16x8 ah, f16x8 al, f16x8 bh, f16x8 bl, f32x4 acc) {
    acc = __builtin_amdgcn_mfma_f32_16x16x32_f16(ah, bh, acc, 0, 0, 0);
    acc = __builtin_amdgcn_mfma_f32_16x16x32_f16(al, bh, acc, 0, 0, 0);
    acc = __builtin_amdgcn_mfma_f32_16x16x32_f16(ah, bl, acc, 0, 0, 0);
    return acc;
}

// packed f16x2 atomic add (native global_atomic_pk_add_f16 on gfx950)
__device__ __forceinline__ void pk_atomic_add(f16* addr, float a0, float a1) {
    __half2 hv = __floats2half2_rn(a0, a1);
    unsafeAtomicAdd((__half2*)addr, hv);
}

// ---- compose: Wcomb = eW2@nW1_bot, Wx = eW2@cW1, bvec = eb2@nW1_bot, bx = eb2@cW1+cb1 ----
__global__ __launch_bounds__(256) void compose_kernel(
    const float* __restrict__ eW2, const float* __restrict__ eb2,
    const float* __restrict__ nW1, const float* __restrict__ cW1,
    const float* __restrict__ cb1,
    float* __restrict__ Wcmb, float* __restrict__ Wx,
    float* __restrict__ bvec, float* __restrict__ bx)
{
    const int gid = blockIdx.x * 256 + threadIdx.x;   // 33024 total
    if (gid < 16384) {
        const int k = gid >> 7, j = gid & 127;
        float s = 0.f;
        for (int t2 = 0; t2 < 128; ++t2) s += eW2[k * 128 + t2] * nW1[(128 + t2) * 128 + j];
        Wcmb[gid] = s;
    } else if (gid < 32768) {
        const int e = gid - 16384;
        const int k = e >> 7, j = e & 127;
        float s = 0.f;
        for (int t2 = 0; t2 < 128; ++t2) s += eW2[k * 128 + t2] * cW1[t2 * 128 + j];
        Wx[e] = s;
    } else if (gid < 32896) {
        const int j = gid - 32768;
        float s = 0.f;
        for (int k = 0; k < 128; ++k) s += eb2[k] * nW1[(128 + k) * 128 + j];
        bvec[j] = s;
    } else if (gid < 33024) {
        const int j = gid - 32896;
        float s = cb1[j];
        for (int k = 0; k < 128; ++k) s += eb2[k] * cW1[k * 128 + j];
        bx[j] = s;
    }
}

// ---- prep: swizzle weights into fragment-order hi/lo f16 planes ----
__global__ __launch_bounds__(256) void prep_kernel(
    const float* __restrict__ eW1, const float* __restrict__ nW1,
    const float* __restrict__ nW2, const float* __restrict__ vW1,
    const float* __restrict__ Wcmb, const float* __restrict__ Wx,
    f16* __restrict__ Wpres, f16* __restrict__ nW1cs,
    f16* __restrict__ nW2s, f16* __restrict__ vW1s, f16* __restrict__ Wxs)
{
    const int gid = blockIdx.x * 256 + threadIdx.x;   // 114688 total
    int K32, e, which; f16* out;
    if (gid < 32768)       { which = 0; out = Wpres; K32 = 4; e = gid; }
    else if (gid < 65536)  { which = 1; out = nW1cs; K32 = 8; e = gid - 32768; }
    else if (gid < 81920)  { which = 2; out = nW2s;  K32 = 4; e = gid - 65536; }
    else if (gid < 98304)  { which = 3; out = vW1s;  K32 = 4; e = gid - 81920; }
    else                   { which = 4; out = Wxs;   K32 = 4; e = gid - 98304; }
    const int per = 512 * K32;
    const int ct = e / per, rem = e % per;
    const int kk = rem >> 9, lane = (rem >> 3) & 63, j = rem & 7;
    const int col = ct * 16 + (lane & 15);
    const int k = kk * 32 + ((lane >> 4) & 3) * 8 + j;
    float v;
    if (which == 0)      v = (col < 128) ? eW1[k * 128 + col] : eW1[(128 + k) * 128 + (col - 128)];
    else if (which == 1) v = (k < 128) ? nW1[k * 128 + col] : Wcmb[(k - 128) * 128 + col];
    else if (which == 2) v = nW2[k * 128 + col];
    else if (which == 3) v = vW1[k * 128 + col];
    else                 v = Wx[k * 128 + col];
    f16 h, l; split_f(v, h, l);
    const int base = ((ct * K32 + kk) * 2) * 512 + lane * 8 + j;
    out[base] = h;
    out[base + 512] = l;
}

// ---- sort pipeline: counting sort of edges by source row ----
__global__ __launch_bounds__(256) void hist_kernel(const int* __restrict__ eidx,
                                                   int* __restrict__ deg) {
    const int e = blockIdx.x * 256 + threadIdx.x;
    if (e < E_EDGES) atomicAdd(&deg[eidx[e]], 1);
}

__global__ __launch_bounds__(256) void scan1_kernel(const int* __restrict__ deg,
                                                    int* __restrict__ locEx,
                                                    int* __restrict__ blockSum) {
    __shared__ int s[256];
    const int t = threadIdx.x;
    const int gid = blockIdx.x * 256 + t;
    const int v = deg[gid];
    s[t] = v;
    __syncthreads();
    for (int off = 1; off < 256; off <<= 1) {
        const int add = (t >= off) ? s[t - off] : 0;
        __syncthreads();
        s[t] += add;
        __syncthreads();
    }
    locEx[gid] = s[t] - v;
    if (t == 255) blockSum[blockIdx.x] = s[255];
}

__global__ __launch_bounds__(256) void scan2_kernel(const int* __restrict__ blockSum,
                                                    int* __restrict__ blockOff) {
    __shared__ int s[256];
    const int t = threadIdx.x;
    const int v = (t < NBLK) ? blockSum[t] : 0;
    s[t] = v;
    __syncthreads();
    for (int off = 1; off < 256; off <<= 1) {
        const int add = (t >= off) ? s[t - off] : 0;
        __syncthreads();
        s[t] += add;
        __syncthreads();
    }
    if (t < NBLK) blockOff[t] = s[t] - v;
}

__global__ __launch_bounds__(256) void scatter_kernel(const int* __restrict__ eidx,
        const int* __restrict__ locEx, const int* __restrict__ blockOff,
        int* __restrict__ fill, u16* __restrict__ srow, u16* __restrict__ scol) {
    const int e = blockIdx.x * 256 + threadIdx.x;
    if (e >= E_EDGES) return;
    const int r = eidx[e], c = eidx[E_EDGES + e];
    const int pos = blockOff[r >> 8] + locEx[r] + atomicAdd(&fill[r], 1);
    srow[pos] = (u16)r;
    scol[pos] = (u16)c;
}

// ---- embedding (f32 VALU, tiny) ----
__global__ __launch_bounds__(256) void embed_kernel(
    const float* __restrict__ h_in, const float* __restrict__ embW,
    const float* __restrict__ embb, float* __restrict__ h)
{
    const int gid = blockIdx.x * 256 + threadIdx.x;
    if (gid >= N_NODES * 128) return;
    const int n = gid >> 7, j = gid & 127;
    float s = embb[j];
#pragma unroll
    for (int p = 0; p < 16; ++p) s += h_in[n * 16 + p] * embW[p * 128 + j];
    h[gid] = s;
}

// staging helper: split 8 f32 into hi/lo octet pair at dst
__device__ __forceinline__ void stage8(const float* src, f16* dst) {
    const float4 f0 = *(const float4*)src;
    const float4 f1 = *(const float4*)(src + 4);
    const float xs[8] = {f0.x, f0.y, f0.z, f0.w, f1.x, f1.y, f1.z, f1.w};
    f16x8 vh, vl;
#pragma unroll
    for (int i = 0; i < 8; ++i) { f16 hh, ll; split_f(xs[i], hh, ll); vh[i] = hh; vl[i] = ll; }
    *(f16x8*)dst = vh;
    *(f16x8*)(dst + 8) = vl;
}

// ---- pre: Apre = f16(h@eW1_top + eb1) ; Bpre = f16(h@eW1_bot) (layer 1 only) ----
__global__ __launch_bounds__(256, 4) void pre_kernel(
    const float* __restrict__ h, const f16* __restrict__ Wpres,
    const float* __restrict__ eb1,
    f16* __restrict__ Apre, f16* __restrict__ Bpre)
{
    constexpr int S = 264;
    __shared__ f16 smA[64 * S];
    const int t = threadIdx.x;
    const int base = blockIdx.x * 64;
    const int lane = t & 63, w = t >> 6, qq = lane >> 4, nn = lane & 15;

#pragma unroll
    for (int it = 0; it < 4; ++it) {
        const int idx = it * 256 + t;
        const int el = idx >> 4, seg = idx & 15;
        const int node = base + el;
        f16* dst = &smA[el * S + seg * 16];
        if (node < N_NODES) {
            stage8(h + (size_t)node * 128 + seg * 8, dst);
        } else {
            *(f16x8*)dst = (f16x8)(f16)0.f;
            *(f16x8*)(dst + 8) = (f16x8)(f16)0.f;
        }
    }
    __syncthreads();

#pragma unroll
    for (int half = 0; half < 2; ++half) {
        f32x4 acc[4][2] = {};
        for (int kk = 0; kk < 4; ++kk) {
            f16x8 Ah[4], Al[4];
#pragma unroll
            for (int rt = 0; rt < 4; ++rt) {
                const f16* ap = &smA[(rt * 16 + nn) * S + (kk * 4 + qq) * 16];
                Ah[rt] = *(const f16x8*)ap;
                Al[rt] = *(const f16x8*)(ap + 8);
            }
#pragma unroll
            for (int c = 0; c < 2; ++c) {
                const int ct = w * 4 + half * 2 + c;
                const f16* bp = Wpres + (size_t)((ct * 4 + kk) * 2) * 512 + lane * 8;
                const f16x8 Bh = *(const f16x8*)bp;
                const f16x8 Bl = *(const f16x8*)(bp + 512);
#pragma unroll
                for (int rt = 0; rt < 4; ++rt)
                    acc[rt][c] = mfma3(Ah[rt], Al[rt], Bh, Bl, acc[rt][c]);
            }
        }
#pragma unroll
        for (int c = 0; c < 2; ++c) {
            const int col = w * 64 + half * 32 + c * 16 + nn;   // 0..255
#pragma unroll
            for (int rt = 0; rt < 4; ++rt) {
#pragma unroll
                for (int r = 0; r < 4; ++r) {
                    const int el = rt * 16 + qq * 4 + r;
                    const int node = base + el;
                    if (node < N_NODES) {
                        const float v = acc[rt][c][r];
                        if (col < 128) Apre[(size_t)node * 128 + col] = (f16)(v + eb1[col]);
                        else           Bpre[(size_t)node * 128 + (col - 128)] = (f16)v;
                    }
                }
            }
        }
    }
}

// ---- edge_z (layer 1): z tile in LDS; 4-deep batched gather (8 loads in flight);
// col-pair merge with wave-uniform flush (pk atomics) ----
__global__ __launch_bounds__(256, 8) void edge_z_kernel(
    const u16* __restrict__ srow, const u16* __restrict__ scol,
    const float* __restrict__ x,
    const f16* __restrict__ Apre, const f16* __restrict__ Bpre,
    const float* __restrict__ wlast,
    f16* __restrict__ zsumh)
{
    constexpr int S2 = 136;
    __shared__ f16 smZ[64 * S2];      // 17408 B, row-major [edge][col]
    __shared__ int smRow[64], smCol[64];
    __shared__ float smRd[64];
    const int t = threadIdx.x;
    const int base = blockIdx.x * 64;
    if (t < 64) {
        const int e = base + t;
        const int r = (int)srow[e], c = (int)scol[e];
        smRow[t] = r; smCol[t] = c;
        const float dx = x[2 * r] - x[2 * c];
        const float dy = x[2 * r + 1] - x[2 * c + 1];
        smRd[t] = dx * dx + dy * dy;
    }
    __syncthreads();

    const int seg = t & 15, el0 = t >> 4;
    const float4 w0 = *(const float4*)(wlast + seg * 8);
    const float4 w1 = *(const float4*)(wlast + seg * 8 + 4);
    const float wl[8] = {w0.x, w0.y, w0.z, w0.w, w1.x, w1.y, w1.z, w1.w};
    // batched gather: all 8 loads issued before any consumption (MLP=8)
    f16x8 AV[4], BV[4];
#pragma unroll
    for (int it = 0; it < 4; ++it) {
        const int el = it * 16 + el0;
        AV[it] = *(const f16x8*)(Apre + (size_t)smRow[el] * 128 + seg * 8);
        BV[it] = *(const f16x8*)(Bpre + (size_t)smCol[el] * 128 + seg * 8);
    }
#pragma unroll
    for (int it = 0; it < 4; ++it) {
        const int el = it * 16 + el0;
        const float rd = smRd[el];
        f16x8 vz;
#pragma unroll
        for (int i = 0; i < 8; ++i)
            vz[i] = (f16)fmaxf((float)AV[it][i] + (float)BV[it][i] + rd * wl[i], 0.f);
        *(f16x8*)&smZ[el * S2 + seg * 8] = vz;
    }
    __syncthreads();

    const int p = t & 63, g = t >> 6;
    float a0 = 0.f, a1 = 0.f;
    int prev = smRow[g * 16];
#pragma unroll
    for (int e = g * 16; e < g * 16 + 16; ++e) {
        const int rw = smRow[e];
        if (rw != prev) {
            pk_atomic_add(&zsumh[(size_t)prev * 128 + 2 * p], a0, a1);
            a0 = a1 = 0.f; prev = rw;
        }
        const f16x2 v = *(const f16x2*)&smZ[e * S2 + 2 * p];
        a0 += (float)v[0]; a1 += (float)v[1];
    }
    pk_atomic_add(&zsumh[(size_t)prev * 128 + 2 * p], a0, a1);
}

// ---- edge_coord (layer 2): batched-gather z tile + merge + coord MFMA (LB 8) ----
__global__ __launch_bounds__(256, 8) void edge_coord_kernel(
    const u16* __restrict__ srow, const u16* __restrict__ scol,
    const float* __restrict__ x,
    const f16* __restrict__ Apre, const f16* __restrict__ Bpre,
    const float* __restrict__ wlast,
    const f16* __restrict__ Wxs, const float* __restrict__ bx,
    const float* __restrict__ cW2, const float* __restrict__ cb2,
    f16* __restrict__ zsumh, float* __restrict__ scat)
{
    constexpr int S2 = 136;
    __shared__ f16 smZ[64 * S2];      // 17408 B
    __shared__ int smRow[64], smCol[64];
    __shared__ float smRd[64], smP2x[64], smP2y[64];
    __shared__ float smPart[4][64];

    const int t = threadIdx.x;
    const int base = blockIdx.x * 64;
    const int lane = t & 63, w = t >> 6, qq = lane >> 4, nn = lane & 15;

    if (t < 64) {
        const int e = base + t;
        const int r = (int)srow[e], c = (int)scol[e];
        smRow[t] = r; smCol[t] = c;
        const float dx = x[2 * r] - x[2 * c];
        const float dy = x[2 * r + 1] - x[2 * c + 1];
        smRd[t] = dx * dx + dy * dy;
        smP2x[t] = dx * dx - dy * dy;     // rel_dist*cos(2θ) exactly
        smP2y[t] = 2.0f * dx * dy;        // rel_dist*sin(2θ) exactly
    }
    __syncthreads();

    {
        const int seg = t & 15, el0 = t >> 4;
        const float4 w0 = *(const float4*)(wlast + seg * 8);
        const float4 w1 = *(const float4*)(wlast + seg * 8 + 4);
        const float wl[8] = {w0.x, w0.y, w0.z, w0.w, w1.x, w1.y, w1.z, w1.w};
        f16x8 AV[4], BV[4];
#pragma unroll
        for (int it = 0; it < 4; ++it) {
            const int el = it * 16 + el0;
            AV[it] = *(const f16x8*)(Apre + (size_t)smRow[el] * 128 + seg * 8);
            BV[it] = *(const f16x8*)(Bpre + (size_t)smCol[el] * 128 + seg * 8);
        }
#pragma unroll
        for (int it = 0; it < 4; ++it) {
            const int el = it * 16 + el0;
            const float rd = smRd[el];
            f16x8 vz;
#pragma unroll
            for (int i = 0; i < 8; ++i)
                vz[i] = (f16)fmaxf((float)AV[it][i] + (float)BV[it][i] + rd * wl[i], 0.f);
            *(f16x8*)&smZ[el * S2 + seg * 8] = vz;
        }
    }
    __syncthreads();

    {
        const int p = t & 63, g = t >> 6;
        float a0 = 0.f, a1 = 0.f;
        int prev = smRow[g * 16];
#pragma unroll
        for (int e = g * 16; e < g * 16 + 16; ++e) {
            const int rw = smRow[e];
            if (rw != prev) {
                pk_atomic_add(&zsumh[(size_t)prev * 128 + 2 * p], a0, a1);
                a0 = a1 = 0.f; prev = rw;
            }
            const f16x2 v = *(const f16x2*)&smZ[e * S2 + 2 * p];
            a0 += (float)v[0]; a1 += (float)v[1];
        }
        pk_atomic_add(&zsumh[(size_t)prev * 128 + 2 * p], a0, a1);
    }

    // ---- coord: co = relu(z @ Wx + bx) @ cW2 + cb2 ; scatter rel_pos2*co ----
    f32x4 acc3[4][2] = {};
    for (int kk = 0; kk < 4; ++kk) {
        f16x8 A[4];
#pragma unroll
        for (int rt = 0; rt < 4; ++rt)
            A[rt] = *(const f16x8*)&smZ[(rt * 16 + nn) * S2 + (kk * 4 + qq) * 8];
#pragma unroll
        for (int c = 0; c < 2; ++c) {
            const int ct = w * 2 + c;
            const f16x8 Bh = *(const f16x8*)(Wxs + (size_t)((ct * 4 + kk) * 2) * 512 + lane * 8);
#pragma unroll
            for (int rt = 0; rt < 4; ++rt)
                acc3[rt][c] = __builtin_amdgcn_mfma_f32_16x16x32_f16(A[rt], Bh, acc3[rt][c], 0, 0, 0);
        }
    }
    float p3[4][4];
#pragma unroll
    for (int rt = 0; rt < 4; ++rt)
#pragma unroll
        for (int r = 0; r < 4; ++r) p3[rt][r] = 0.f;
#pragma unroll
    for (int c = 0; c < 2; ++c) {
        const int col = w * 32 + c * 16 + nn;
        const float c1 = bx[col];
        const float w2 = cW2[col];
#pragma unroll
        for (int rt = 0; rt < 4; ++rt)
#pragma unroll
            for (int r = 0; r < 4; ++r)
                p3[rt][r] += fmaxf(acc3[rt][c][r] + c1, 0.f) * w2;
    }
#pragma unroll
    for (int off = 1; off < 16; off <<= 1)
#pragma unroll
        for (int rt = 0; rt < 4; ++rt)
#pragma unroll
            for (int r = 0; r < 4; ++r) p3[rt][r] += __shfl_xor(p3[rt][r], off);
    if (nn == 0) {
#pragma unroll
        for (int rt = 0; rt < 4; ++rt)
#pragma unroll
            for (int r = 0; r < 4; ++r)
                smPart[w][rt * 16 + qq * 4 + r] = p3[rt][r];
    }
    __syncthreads();
    if (t < 64) {
        const float co = smPart[0][t] + smPart[1][t] + smPart[2][t] + smPart[3][t] + cb2[0];
        const int rw = smRow[t];
        atomicAdd(&scat[2 * rw],     smP2x[t] * co);
        atomicAdd(&scat[2 * rw + 1], smP2y[t] * co);
    }
}

// ---- node core: computes h_new, writes h, leaves h_new staged in smA (fragment
// layout, hi/lo split). Shared by both fused kernels. ----
__device__ __forceinline__ void node_core(
    float* __restrict__ h, f16* __restrict__ zsumh,
    const int* __restrict__ deg,
    const f16* __restrict__ nW1cs, const float* __restrict__ nb1,
    const float* __restrict__ bvec,
    const f16* __restrict__ nW2s, const float* __restrict__ nb2,
    f16* smA, float* smDeg, int t, int base)
{
    constexpr int S = 264;
    const int lane = t & 63, w = t >> 6, qq = lane >> 4, nn = lane & 15;

    if (t < 64) smDeg[t] = (float)deg[base + t];   // base+63 <= 50047 < NBINS, safe

    f32x4 acc1[4][2] = {};
    for (int chunk = 0; chunk < 2; ++chunk) {
        if (chunk) __syncthreads();
#pragma unroll
        for (int it = 0; it < 4; ++it) {
            const int idx = it * 256 + t;
            const int el = idx >> 4, seg = idx & 15;
            const int node = base + el;
            f16* dst = &smA[el * S + seg * 16];
            if (node < N_NODES) {
                if (chunk == 0) {
                    stage8(h + (size_t)node * 128 + seg * 8, dst);
                } else {
                    f16* src = zsumh + (size_t)node * 128 + seg * 8;
                    const f16x8 v = *(const f16x8*)src;
                    *(f16x8*)dst = v;                       // hi plane = f16 value
                    *(f16x8*)(dst + 8) = (f16x8)(f16)0.f;   // lo plane = 0
                    *(f16x8*)src = (f16x8)(f16)0.f;         // zero zsumh in place
                }
            } else {
                *(f16x8*)dst = (f16x8)(f16)0.f;
                *(f16x8*)(dst + 8) = (f16x8)(f16)0.f;
            }
        }
        __syncthreads();
        for (int kk = 0; kk < 4; ++kk) {
            f16x8 Ah[4], Al[4];
#pragma unroll
            for (int rt = 0; rt < 4; ++rt) {
                const f16* ap = &smA[(rt * 16 + nn) * S + (kk * 4 + qq) * 16];
                Ah[rt] = *(const f16x8*)ap;
                Al[rt] = *(const f16x8*)(ap + 8);
            }
            const int kkg = chunk * 4 + kk;
#pragma unroll
            for (int c = 0; c < 2; ++c) {
                const int ct = w * 2 + c;
                const f16* bp = nW1cs + (size_t)((ct * 8 + kkg) * 2) * 512 + lane * 8;
                const f16x8 Bh = *(const f16x8*)bp;
                const f16x8 Bl = *(const f16x8*)(bp + 512);
#pragma unroll
                for (int rt = 0; rt < 4; ++rt)
                    acc1[rt][c] = mfma3(Ah[rt], Al[rt], Bh, Bl, acc1[rt][c]);
            }
        }
    }
    __syncthreads();
#pragma unroll
    for (int c = 0; c < 2; ++c) {
        const int col = w * 32 + c * 16 + nn;
        const float b1 = nb1[col];
        const float bv = bvec[col];
#pragma unroll
        for (int rt = 0; rt < 4; ++rt) {
#pragma unroll
            for (int r = 0; r < 4; ++r) {
                const int el = rt * 16 + qq * 4 + r;
                const float z = fmaxf(acc1[rt][c][r] + b1 + smDeg[el] * bv, 0.f);
                f16 zh, zl; split_f(z, zh, zl);
                f16* zp = &smA[el * S + (col >> 3) * 16 + (col & 7)];
                zp[0] = zh; zp[8] = zl;
            }
        }
    }
    __syncthreads();

    f32x4 acc2[4][2] = {};
    for (int kk = 0; kk < 4; ++kk) {
        f16x8 Ah[4], Al[4];
#pragma unroll
        for (int rt = 0; rt < 4; ++rt) {
            const f16* ap = &smA[(rt * 16 + nn) * S + (kk * 4 + qq) * 16];
            Ah[rt] = *(const f16x8*)ap;
            Al[rt] = *(const f16x8*)(ap + 8);
        }
#pragma unroll
        for (int c = 0; c < 2; ++c) {
            const int ct = w * 2 + c;
            const f16* bp = nW2s + (size_t)((ct * 4 + kk) * 2) * 512 + lane * 8;
            const f16x8 Bh = *(const f16x8*)bp;
            const f16x8 Bl = *(const f16x8*)(bp + 512);
#pragma unroll
            for (int rt = 0; rt < 4; ++rt)
                acc2[rt][c] = mfma3(Ah[rt], Al[rt], Bh, Bl, acc2[rt][c]);
        }
    }
    __syncthreads();   // smA z reads done -> overwrite with h_new
#pragma unroll
    for (int c = 0; c < 2; ++c) {
        const int col = w * 32 + c * 16 + nn;
        const float b2 = nb2[col];
#pragma unroll
        for (int rt = 0; rt < 4; ++rt) {
#pragma unroll
            for (int r = 0; r < 4; ++r) {
                const int el = rt * 16 + qq * 4 + r;
                const int node = base + el;
                if (node < N_NODES) {
                    const size_t ix = (size_t)node * 128 + col;
                    const float hn = h[ix] + acc2[rt][c][r] + b2;
                    h[ix] = hn;
                    f16 hh, hl; split_f(hn, hh, hl);
                    f16* hp = &smA[el * S + (col >> 3) * 16 + (col & 7)];
                    hp[0] = hh; hp[8] = hl;
                }
                // node >= N: stale smA rows harmless (outputs guarded by node<N)
            }
        }
    }
    __syncthreads();   // h_new staged for the fused consumer GEMM
}

// ---- node_pre (layer 1): node update fused with pre-GEMM for layer 2 ----
__global__ __launch_bounds__(256, 4) void node_pre_kernel(
    float* __restrict__ h, f16* __restrict__ zsumh,
    const int* __restrict__ deg,
    const f16* __restrict__ nW1cs, const float* __restrict__ nb1,
    const float* __restrict__ bvec,
    const f16* __restrict__ nW2s, const float* __restrict__ nb2,
    const f16* __restrict__ Wpres, const float* __restrict__ eb1,
    f16* __restrict__ Apre, f16* __restrict__ Bpre)
{
    constexpr int S = 264;
    __shared__ f16 smA[64 * S];
    __shared__ float smDeg[64];
    const int t = threadIdx.x;
    const int base = blockIdx.x * 64;
    const int lane = t & 63, w = t >> 6, qq = lane >> 4, nn = lane & 15;

    node_core(h, zsumh, deg, nW1cs, nb1, bvec, nW2s, nb2, smA, smDeg, t, base);

    // pre-GEMM on staged h_new: Apre = h@eW1_top + eb1, Bpre = h@eW1_bot
#pragma unroll
    for (int half = 0; half < 2; ++half) {
        f32x4 acc[4][2] = {};
        for (int kk = 0; kk < 4; ++kk) {
            f16x8 Ah[4], Al[4];
#pragma unroll
            for (int rt = 0; rt < 4; ++rt) {
                const f16* ap = &smA[(rt * 16 + nn) * S + (kk * 4 + qq) * 16];
                Ah[rt] = *(const f16x8*)ap;
                Al[rt] = *(const f16x8*)(ap + 8);
            }
#pragma unroll
            for (int c = 0; c < 2; ++c) {
                const int ct = w * 4 + half * 2 + c;
                const f16* bp = Wpres + (size_t)((ct * 4 + kk) * 2) * 512 + lane * 8;
                const f16x8 Bh = *(const f16x8*)bp;
                const f16x8 Bl = *(const f16x8*)(bp + 512);
#pragma unroll
                for (int rt = 0; rt < 4; ++rt)
                    acc[rt][c] = mfma3(Ah[rt], Al[rt], Bh, Bl, acc[rt][c]);
            }
        }
#pragma unroll
        for (int c = 0; c < 2; ++c) {
            const int col = w * 64 + half * 32 + c * 16 + nn;   // 0..255
#pragma unroll
            for (int rt = 0; rt < 4; ++rt) {
#pragma unroll
                for (int r = 0; r < 4; ++r) {
                    const int el = rt * 16 + qq * 4 + r;
                    const int node = base + el;
                    if (node < N_NODES) {
                        const float v = acc[rt][c][r];
                        if (col < 128) Apre[(size_t)node * 128 + col] = (f16)(v + eb1[col]);
                        else           Bpre[(size_t)node * 128 + (col - 128)] = (f16)v;
                    }
                }
            }
        }
    }
}

// ---- node_final (layer 2): node update fused with v-MLP + normalize + x copy ----
__global__ __launch_bounds__(256, 4) void node_final_kernel(
    float* __restrict__ h, f16* __restrict__ zsumh,
    const int* __restrict__ deg,
    const f16* __restrict__ nW1cs, const float* __restrict__ nb1,
    const float* __restrict__ bvec,
    const f16* __restrict__ nW2s, const float* __restrict__ nb2,
    const f16* __restrict__ vW1s, const float* __restrict__ vb1,
    const float* __restrict__ vW2, const float* __restrict__ vb2,
    const float* __restrict__ scat, const float* __restrict__ x,
    float* __restrict__ out)
{
    constexpr int S = 264;
    __shared__ f16 smA[64 * S];
    __shared__ float smDeg[64];
    const int t = threadIdx.x;
    const int base = blockIdx.x * 64;
    const int lane = t & 63, w = t >> 6, qq = lane >> 4, nn = lane & 15;

    node_core(h, zsumh, deg, nW1cs, nb1, bvec, nW2s, nb2, smA, smDeg, t, base);

    // v-GEMM on staged h_new: z = relu(h@vW1 + vb1) -> smA
    f32x4 acc1[4][2] = {};
    for (int kk = 0; kk < 4; ++kk) {
        f16x8 Ah[4], Al[4];
#pragma unroll
        for (int rt = 0; rt < 4; ++rt) {
            const f16* ap = &smA[(rt * 16 + nn) * S + (kk * 4 + qq) * 16];
            Ah[rt] = *(const f16x8*)ap;
            Al[rt] = *(const f16x8*)(ap + 8);
        }
#pragma unroll
        for (int c = 0; c < 2; ++c) {
            const int ct = w * 2 + c;
            const f16* bp = vW1s + (size_t)((ct * 4 + kk) * 2) * 512 + lane * 8;
            const f16x8 Bh = *(const f16x8*)bp;
            const f16x8 Bl = *(const f16x8*)(bp + 512);
#pragma unroll
            for (int rt = 0; rt < 4; ++rt)
                acc1[rt][c] = mfma3(Ah[rt], Al[rt], Bh, Bl, acc1[rt][c]);
        }
    }
    __syncthreads();
#pragma unroll
    for (int c = 0; c < 2; ++c) {
        const int col = w * 32 + c * 16 + nn;
        const float b1 = vb1[col];
#pragma unroll
        for (int rt = 0; rt < 4; ++rt) {
#pragma unroll
            for (int r = 0; r < 4; ++r) {
                const int el = rt * 16 + qq * 4 + r;
                const float z = fmaxf(acc1[rt][c][r] + b1, 0.f);
                f16 zh, zl; split_f(z, zh, zl);
                f16* zp = &smA[el * S + (col >> 3) * 16 + (col & 7)];
                zp[0] = zh; zp[8] = zl;
            }
        }
    }
    __syncthreads();

    float* out_x = out + (size_t)N_NODES * 128;
    float* out_v = out_x + (size_t)N_NODES * 2;
    if (t < 128) {
        const int node = base + (t >> 1);
        if (node < N_NODES) out_x[node * 2 + (t & 1)] = x[node * 2 + (t & 1)];
    }
    if (t < 128) {
        const int rl = t >> 1, comp = t & 1;
        const int node = base + rl;
        float s = 0.f;
        if (node < N_NODES) {
            s = vb2[comp];
            for (int k = 0; k < 128; ++k) {
                const f16* zp = &smA[rl * S + (k >> 3) * 16 + (k & 7)];
                const float z = (float)zp[0] + (float)zp[8];
                s += z * vW2[k * 2 + comp];
            }
            const float dn = fmaxf((float)smDeg[rl], 1.0f);
            s += scat[node * 2 + comp] / dn;
        }
        const float other = __shfl_xor(s, 1);
        if (node < N_NODES) {
            const float nrm = sqrtf(s * s + other * other);
            out_v[node * 2 + comp] = s / fmaxf(nrm, 1e-12f);
        }
    }
}

extern "C" void kernel_launch(void* const* d_in, const int* in_sizes, int n_in,
                              void* d_out, int out_size, void* d_ws, size_t ws_size,
                              hipStream_t stream) {
    const float* h_in = (const float*)d_in[0];
    const float* x    = (const float*)d_in[1];
    const int*   eidx = (const int*)d_in[2];
    const float* embW = (const float*)d_in[3];
    const float* embb = (const float*)d_in[4];
    const float* eW1  = (const float*)d_in[5];
    const float* eb1  = (const float*)d_in[6];
    const float* eW2  = (const float*)d_in[7];
    const float* eb2  = (const float*)d_in[8];
    const float* nW1  = (const float*)d_in[9];
    const float* nb1  = (const float*)d_in[10];
    const float* nW2  = (const float*)d_in[11];
    const float* nb2  = (const float*)d_in[12];
    const float* vW1  = (const float*)d_in[13];
    const float* vb1  = (const float*)d_in[14];
    const float* vW2  = (const float*)d_in[15];
    const float* vb2  = (const float*)d_in[16];
    const float* cW1  = (const float*)d_in[17];
    const float* cb1  = (const float*)d_in[18];
    const float* cW2  = (const float*)d_in[19];
    const float* cb2  = (const float*)d_in[20];

    char* ws = (char*)d_ws;
    int* deg    = (int*)(ws + OFF_DEG);
    int* locEx  = (int*)(ws + OFF_LOCEX);
    int* bsum   = (int*)(ws + OFF_BSUM);
    int* boff   = (int*)(ws + OFF_BOFF);
    int* fill   = (int*)(ws + OFF_FILL);
    float* scat = (float*)(ws + OFF_SCAT);
    u16* srow   = (u16*)(ws + OFF_SROW);
    u16* scol   = (u16*)(ws + OFF_SCOL);
    f16* zsumh  = (f16*)(ws + OFF_ZSUM);
    f16* Apre   = (f16*)(ws + OFF_APRE);
    f16* Bpre   = (f16*)(ws + OFF_BPRE);
    float* Wcmb = (float*)(ws + OFF_CMB);
    float* Wx   = (float*)(ws + OFF_WX);
    float* bvec = (float*)(ws + OFF_BVEC);
    float* bx   = (float*)(ws + OFF_BX);
    f16* Wpres  = (f16*)(ws + OFF_WSWZ);
    f16* nW1cs  = Wpres + 65536;
    f16* nW2s   = nW1cs + 65536;
    f16* vW1s   = nW2s + 32768;
    f16* Wxs    = vW1s + 32768;

    // h lives in d_out's h-region: final copy is free
    float* hcur = (float*)d_out;

    // zero deg/locEx/bsum/boff/fill/scat (1 MB) + zsumh (12.8 MB; node kernels
    // re-zero zsumh in-place every call thereafter)
    hipMemsetAsync(ws, 0, OFF_SROW, stream);
    hipMemsetAsync(zsumh, 0, ZSH_BYTES, stream);

    compose_kernel<<<129, 256, 0, stream>>>(eW2, eb2, nW1, cW1, cb1, Wcmb, Wx, bvec, bx);
    prep_kernel<<<448, 256, 0, stream>>>(eW1, nW1, nW2, vW1, Wcmb, Wx,
                                         Wpres, nW1cs, nW2s, vW1s, Wxs);
    hist_kernel<<<(E_EDGES + 255) / 256, 256, 0, stream>>>(eidx, deg);
    scan1_kernel<<<NBLK, 256, 0, stream>>>(deg, locEx, bsum);
    scan2_kernel<<<1, 256, 0, stream>>>(bsum, boff);
    scatter_kernel<<<(E_EDGES + 255) / 256, 256, 0, stream>>>(eidx, locEx, boff,
                                                              fill, srow, scol);
    embed_kernel<<<(N_NODES * 128 + 255) / 256, 256, 0, stream>>>(h_in, embW, embb, hcur);

    const float* wlast = eW1 + 256 * 128;   // rel_dist row of eW1

    // layer 1
    pre_kernel<<<(N_NODES + 63) / 64, 256, 0, stream>>>(hcur, Wpres, eb1, Apre, Bpre);
    edge_z_kernel<<<E_EDGES / 64, 256, 0, stream>>>(srow, scol, x, Apre, Bpre, wlast, zsumh);
    node_pre_kernel<<<(N_NODES + 63) / 64, 256, 0, stream>>>(hcur, zsumh, deg,
        nW1cs, nb1, bvec, nW2s, nb2, Wpres, eb1, Apre, Bpre);

    // layer 2 (with coord + scatter); zsumh zeroed in-place by node_pre
    edge_coord_kernel<<<E_EDGES / 64, 256, 0, stream>>>(srow, scol, x, Apre, Bpre, wlast,
        Wxs, bx, cW2, cb2, zsumh, scat);
    node_final_kernel<<<(N_NODES + 63) / 64, 256, 0, stream>>>(hcur, zsumh, deg,
        nW1cs, nb1, bvec, nW2s, nb2, vW1s, vb1, vW2, vb2, scat, x, (float*)d_out);
}

// Round 20
// 557.170 us; speedup vs baseline: 1.0258x; 1.0081x over previous
//
#include <hip/hip_runtime.h>
#include <hip/hip_fp16.h>

typedef _Float16 f16;
typedef unsigned short u16;
typedef unsigned int u32;
typedef f16 f16x2 __attribute__((ext_vector_type(2)));
typedef f16 f16x8 __attribute__((ext_vector_type(8)));
typedef float f32x4 __attribute__((ext_vector_type(4)));

constexpr int N_NODES = 50000;
constexpr int E_EDGES = 800000;
constexpr int NBINS   = 50176;            // 196 * 256
constexpr int NBLK    = 196;

// workspace layout (bytes) -- total 55,995,008 B, UNDER the known-good 59.13 MB
constexpr size_t OFF_DEG   = 0;           // NBINS*4
constexpr size_t OFF_LOCEX = 200704;      // NBINS*4
constexpr size_t OFF_BSUM  = 401408;      // 1024
constexpr size_t OFF_BOFF  = 402432;      // 1024
constexpr size_t OFF_FILL  = 403456;      // NBINS*4
constexpr size_t OFF_SCAT  = 604160;      // N*2*4
constexpr size_t OFF_SEDGE = 1004160;     // E*4 (u32: row | col<<16) [was srow+scol 2x E*2]
constexpr size_t OFF_ZSUM  = 4204160;     // N*128*2 (f16, pk atomics; region sized f32 for slack)
constexpr size_t ZSH_BYTES = (size_t)N_NODES * 128 * 2;
constexpr size_t ZS_BYTES  = (size_t)N_NODES * 128 * 4;
constexpr size_t OFF_APRE  = OFF_ZSUM + ZS_BYTES;     // 29,804,160: N*128*2 (f16)
constexpr size_t OFF_BPRE  = OFF_APRE + (size_t)N_NODES * 128 * 2;  // 42,604,160
constexpr size_t OFF_CMB   = OFF_BPRE + (size_t)N_NODES * 128 * 2;  // 55,404,160
constexpr size_t OFF_WX    = OFF_CMB + 65536;
constexpr size_t OFF_BVEC  = OFF_WX + 65536;
constexpr size_t OFF_BX    = OFF_BVEC + 512;
constexpr size_t OFF_WSWZ  = OFF_BX + 512;            // 55,536,256 + 458,752 = 55,995,008

// f32 -> f16 hi/lo split: x ~= hi + lo, |err| <= 2^-22 |x|
__device__ __forceinline__ void split_f(float x, f16& h, f16& l) {
    h = (f16)x;
    l = (f16)(x - (float)h);
}

__device__ __forceinline__ f32x4 mfma3(f16x8 ah, f16x8 al, f16x8 bh, f16x8 bl, f32x4 acc) {
    acc = __builtin_amdgcn_mfma_f32_16x16x32_f16(ah, bh, acc, 0, 0, 0);
    acc = __builtin_amdgcn_mfma_f32_16x16x32_f16(al, bh, acc, 0, 0, 0);
    acc = __builtin_amdgcn_mfma_f32_16x16x32_f16(ah, bl, acc, 0, 0, 0);
    return acc;
}

// packed f16x2 atomic add (native global_atomic_pk_add_f16 on gfx950)
__device__ __forceinline__ void pk_atomic_add(f16* addr, float a0, float a1) {
    __half2 hv = __floats2half2_rn(a0, a1);
    unsafeAtomicAdd((__half2*)addr, hv);
}

// ---- compose: Wcomb = eW2@nW1_bot, Wx = eW2@cW1, bvec = eb2@nW1_bot, bx = eb2@cW1+cb1 ----
__global__ __launch_bounds__(256) void compose_kernel(
    const float* __restrict__ eW2, const float* __restrict__ eb2,
    const float* __restrict__ nW1, const float* __restrict__ cW1,
    const float* __restrict__ cb1,
    float* __restrict__ Wcmb, float* __restrict__ Wx,
    float* __restrict__ bvec, float* __restrict__ bx)
{
    const int gid = blockIdx.x * 256 + threadIdx.x;   // 33024 total
    if (gid < 16384) {
        const int k = gid >> 7, j = gid & 127;
        float s = 0.f;
        for (int t2 = 0; t2 < 128; ++t2) s += eW2[k * 128 + t2] * nW1[(128 + t2) * 128 + j];
        Wcmb[gid] = s;
    } else if (gid < 32768) {
        const int e = gid - 16384;
        const int k = e >> 7, j = e & 127;
        float s = 0.f;
        for (int t2 = 0; t2 < 128; ++t2) s += eW2[k * 128 + t2] * cW1[t2 * 128 + j];
        Wx[e] = s;
    } else if (gid < 32896) {
        const int j = gid - 32768;
        float s = 0.f;
        for (int k = 0; k < 128; ++k) s += eb2[k] * nW1[(128 + k) * 128 + j];
        bvec[j] = s;
    } else if (gid < 33024) {
        const int j = gid - 32896;
        float s = cb1[j];
        for (int k = 0; k < 128; ++k) s += eb2[k] * cW1[k * 128 + j];
        bx[j] = s;
    }
}

// ---- prep: swizzle weights into fragment-order hi/lo f16 planes ----
__global__ __launch_bounds__(256) void prep_kernel(
    const float* __restrict__ eW1, const float* __restrict__ nW1,
    const float* __restrict__ nW2, const float* __restrict__ vW1,
    const float* __restrict__ Wcmb, const float* __restrict__ Wx,
    f16* __restrict__ Wpres, f16* __restrict__ nW1cs,
    f16* __restrict__ nW2s, f16* __restrict__ vW1s, f16* __restrict__ Wxs)
{
    const int gid = blockIdx.x * 256 + threadIdx.x;   // 114688 total
    int K32, e, which; f16* out;
    if (gid < 32768)       { which = 0; out = Wpres; K32 = 4; e = gid; }
    else if (gid < 65536)  { which = 1; out = nW1cs; K32 = 8; e = gid - 32768; }
    else if (gid < 81920)  { which = 2; out = nW2s;  K32 = 4; e = gid - 65536; }
    else if (gid < 98304)  { which = 3; out = vW1s;  K32 = 4; e = gid - 81920; }
    else                   { which = 4; out = Wxs;   K32 = 4; e = gid - 98304; }
    const int per = 512 * K32;
    const int ct = e / per, rem = e % per;
    const int kk = rem >> 9, lane = (rem >> 3) & 63, j = rem & 7;
    const int col = ct * 16 + (lane & 15);
    const int k = kk * 32 + ((lane >> 4) & 3) * 8 + j;
    float v;
    if (which == 0)      v = (col < 128) ? eW1[k * 128 + col] : eW1[(128 + k) * 128 + (col - 128)];
    else if (which == 1) v = (k < 128) ? nW1[k * 128 + col] : Wcmb[(k - 128) * 128 + col];
    else if (which == 2) v = nW2[k * 128 + col];
    else if (which == 3) v = vW1[k * 128 + col];
    else                 v = Wx[k * 128 + col];
    f16 h, l; split_f(v, h, l);
    const int base = ((ct * K32 + kk) * 2) * 512 + lane * 8 + j;
    out[base] = h;
    out[base + 512] = l;
}

// ---- sort pipeline: counting sort of edges by source row ----
__global__ __launch_bounds__(256) void hist_kernel(const int* __restrict__ eidx,
                                                   int* __restrict__ deg) {
    const int e = blockIdx.x * 256 + threadIdx.x;
    if (e < E_EDGES) atomicAdd(&deg[eidx[e]], 1);
}

__global__ __launch_bounds__(256) void scan1_kernel(const int* __restrict__ deg,
                                                    int* __restrict__ locEx,
                                                    int* __restrict__ blockSum) {
    __shared__ int s[256];
    const int t = threadIdx.x;
    const int gid = blockIdx.x * 256 + t;
    const int v = deg[gid];
    s[t] = v;
    __syncthreads();
    for (int off = 1; off < 256; off <<= 1) {
        const int add = (t >= off) ? s[t - off] : 0;
        __syncthreads();
        s[t] += add;
        __syncthreads();
    }
    locEx[gid] = s[t] - v;
    if (t == 255) blockSum[blockIdx.x] = s[255];
}

__global__ __launch_bounds__(256) void scan2_kernel(const int* __restrict__ blockSum,
                                                    int* __restrict__ blockOff) {
    __shared__ int s[256];
    const int t = threadIdx.x;
    const int v = (t < NBLK) ? blockSum[t] : 0;
    s[t] = v;
    __syncthreads();
    for (int off = 1; off < 256; off <<= 1) {
        const int add = (t >= off) ? s[t - off] : 0;
        __syncthreads();
        s[t] += add;
        __syncthreads();
    }
    if (t < NBLK) blockOff[t] = s[t] - v;
}

// packed scatter: one random u32 write per edge (was two random u16 writes)
__global__ __launch_bounds__(256) void scatter_kernel(const int* __restrict__ eidx,
        const int* __restrict__ locEx, const int* __restrict__ blockOff,
        int* __restrict__ fill, u32* __restrict__ sedge) {
    const int e = blockIdx.x * 256 + threadIdx.x;
    if (e >= E_EDGES) return;
    const int r = eidx[e], c = eidx[E_EDGES + e];
    const int pos = blockOff[r >> 8] + locEx[r] + atomicAdd(&fill[r], 1);
    sedge[pos] = (u32)r | ((u32)c << 16);
}

// ---- embedding (f32 VALU, tiny) ----
__global__ __launch_bounds__(256) void embed_kernel(
    const float* __restrict__ h_in, const float* __restrict__ embW,
    const float* __restrict__ embb, float* __restrict__ h)
{
    const int gid = blockIdx.x * 256 + threadIdx.x;
    if (gid >= N_NODES * 128) return;
    const int n = gid >> 7, j = gid & 127;
    float s = embb[j];
#pragma unroll
    for (int p = 0; p < 16; ++p) s += h_in[n * 16 + p] * embW[p * 128 + j];
    h[gid] = s;
}

// staging helper: split 8 f32 into hi/lo octet pair at dst
__device__ __forceinline__ void stage8(const float* src, f16* dst) {
    const float4 f0 = *(const float4*)src;
    const float4 f1 = *(const float4*)(src + 4);
    const float xs[8] = {f0.x, f0.y, f0.z, f0.w, f1.x, f1.y, f1.z, f1.w};
    f16x8 vh, vl;
#pragma unroll
    for (int i = 0; i < 8; ++i) { f16 hh, ll; split_f(xs[i], hh, ll); vh[i] = hh; vl[i] = ll; }
    *(f16x8*)dst = vh;
    *(f16x8*)(dst + 8) = vl;
}

// ---- pre: Apre = f16(h@eW1_top + eb1) ; Bpre = f16(h@eW1_bot) (layer 1 only) ----
__global__ __launch_bounds__(256, 4) void pre_kernel(
    const float* __restrict__ h, const f16* __restrict__ Wpres,
    const float* __restrict__ eb1,
    f16* __restrict__ Apre, f16* __restrict__ Bpre)
{
    constexpr int S = 264;
    __shared__ f16 smA[64 * S];
    const int t = threadIdx.x;
    const int base = blockIdx.x * 64;
    const int lane = t & 63, w = t >> 6, qq = lane >> 4, nn = lane & 15;

#pragma unroll
    for (int it = 0; it < 4; ++it) {
        const int idx = it * 256 + t;
        const int el = idx >> 4, seg = idx & 15;
        const int node = base + el;
        f16* dst = &smA[el * S + seg * 16];
        if (node < N_NODES) {
            stage8(h + (size_t)node * 128 + seg * 8, dst);
        } else {
            *(f16x8*)dst = (f16x8)(f16)0.f;
            *(f16x8*)(dst + 8) = (f16x8)(f16)0.f;
        }
    }
    __syncthreads();

#pragma unroll
    for (int half = 0; half < 2; ++half) {
        f32x4 acc[4][2] = {};
        for (int kk = 0; kk < 4; ++kk) {
            f16x8 Ah[4], Al[4];
#pragma unroll
            for (int rt = 0; rt < 4; ++rt) {
                const f16* ap = &smA[(rt * 16 + nn) * S + (kk * 4 + qq) * 16];
                Ah[rt] = *(const f16x8*)ap;
                Al[rt] = *(const f16x8*)(ap + 8);
            }
#pragma unroll
            for (int c = 0; c < 2; ++c) {
                const int ct = w * 4 + half * 2 + c;
                const f16* bp = Wpres + (size_t)((ct * 4 + kk) * 2) * 512 + lane * 8;
                const f16x8 Bh = *(const f16x8*)bp;
                const f16x8 Bl = *(const f16x8*)(bp + 512);
#pragma unroll
                for (int rt = 0; rt < 4; ++rt)
                    acc[rt][c] = mfma3(Ah[rt], Al[rt], Bh, Bl, acc[rt][c]);
            }
        }
#pragma unroll
        for (int c = 0; c < 2; ++c) {
            const int col = w * 64 + half * 32 + c * 16 + nn;   // 0..255
#pragma unroll
            for (int rt = 0; rt < 4; ++rt) {
#pragma unroll
                for (int r = 0; r < 4; ++r) {
                    const int el = rt * 16 + qq * 4 + r;
                    const int node = base + el;
                    if (node < N_NODES) {
                        const float v = acc[rt][c][r];
                        if (col < 128) Apre[(size_t)node * 128 + col] = (f16)(v + eb1[col]);
                        else           Bpre[(size_t)node * 128 + (col - 128)] = (f16)v;
                    }
                }
            }
        }
    }
}

// ---- edge_z (layer 1): z tile in LDS; 4-deep batched gather (8 loads in flight);
// col-pair merge with wave-uniform flush (pk atomics) ----
__global__ __launch_bounds__(256, 8) void edge_z_kernel(
    const u32* __restrict__ sedge,
    const float* __restrict__ x,
    const f16* __restrict__ Apre, const f16* __restrict__ Bpre,
    const float* __restrict__ wlast,
    f16* __restrict__ zsumh)
{
    constexpr int S2 = 136;
    __shared__ f16 smZ[64 * S2];      // 17408 B, row-major [edge][col]
    __shared__ int smRow[64], smCol[64];
    __shared__ float smRd[64];
    const int t = threadIdx.x;
    const int base = blockIdx.x * 64;
    if (t < 64) {
        const u32 v = sedge[base + t];
        const int r = (int)(v & 0xffffu), c = (int)(v >> 16);
        smRow[t] = r; smCol[t] = c;
        const float dx = x[2 * r] - x[2 * c];
        const float dy = x[2 * r + 1] - x[2 * c + 1];
        smRd[t] = dx * dx + dy * dy;
    }
    __syncthreads();

    const int seg = t & 15, el0 = t >> 4;
    const float4 w0 = *(const float4*)(wlast + seg * 8);
    const float4 w1 = *(const float4*)(wlast + seg * 8 + 4);
    const float wl[8] = {w0.x, w0.y, w0.z, w0.w, w1.x, w1.y, w1.z, w1.w};
    // batched gather: all 8 loads issued before any consumption (MLP=8)
    f16x8 AV[4], BV[4];
#pragma unroll
    for (int it = 0; it < 4; ++it) {
        const int el = it * 16 + el0;
        AV[it] = *(const f16x8*)(Apre + (size_t)smRow[el] * 128 + seg * 8);
        BV[it] = *(const f16x8*)(Bpre + (size_t)smCol[el] * 128 + seg * 8);
    }
#pragma unroll
    for (int it = 0; it < 4; ++it) {
        const int el = it * 16 + el0;
        const float rd = smRd[el];
        f16x8 vz;
#pragma unroll
        for (int i = 0; i < 8; ++i)
            vz[i] = (f16)fmaxf((float)AV[it][i] + (float)BV[it][i] + rd * wl[i], 0.f);
        *(f16x8*)&smZ[el * S2 + seg * 8] = vz;
    }
    __syncthreads();

    const int p = t & 63, g = t >> 6;
    float a0 = 0.f, a1 = 0.f;
    int prev = smRow[g * 16];
#pragma unroll
    for (int e = g * 16; e < g * 16 + 16; ++e) {
        const int rw = smRow[e];
        if (rw != prev) {
            pk_atomic_add(&zsumh[(size_t)prev * 128 + 2 * p], a0, a1);
            a0 = a1 = 0.f; prev = rw;
        }
        const f16x2 v = *(const f16x2*)&smZ[e * S2 + 2 * p];
        a0 += (float)v[0]; a1 += (float)v[1];
    }
    pk_atomic_add(&zsumh[(size_t)prev * 128 + 2 * p], a0, a1);
}

// ---- edge_coord (layer 2): batched-gather z tile + merge + coord MFMA (LB 8) ----
__global__ __launch_bounds__(256, 8) void edge_coord_kernel(
    const u32* __restrict__ sedge,
    const float* __restrict__ x,
    const f16* __restrict__ Apre, const f16* __restrict__ Bpre,
    const float* __restrict__ wlast,
    const f16* __restrict__ Wxs, const float* __restrict__ bx,
    const float* __restrict__ cW2, const float* __restrict__ cb2,
    f16* __restrict__ zsumh, float* __restrict__ scat)
{
    constexpr int S2 = 136;
    __shared__ f16 smZ[64 * S2];      // 17408 B
    __shared__ int smRow[64], smCol[64];
    __shared__ float smRd[64], smP2x[64], smP2y[64];
    __shared__ float smPart[4][64];

    const int t = threadIdx.x;
    const int base = blockIdx.x * 64;
    const int lane = t & 63, w = t >> 6, qq = lane >> 4, nn = lane & 15;

    if (t < 64) {
        const u32 v = sedge[base + t];
        const int r = (int)(v & 0xffffu), c = (int)(v >> 16);
        smRow[t] = r; smCol[t] = c;
        const float dx = x[2 * r] - x[2 * c];
        const float dy = x[2 * r + 1] - x[2 * c + 1];
        smRd[t] = dx * dx + dy * dy;
        smP2x[t] = dx * dx - dy * dy;     // rel_dist*cos(2θ) exactly
        smP2y[t] = 2.0f * dx * dy;        // rel_dist*sin(2θ) exactly
    }
    __syncthreads();

    {
        const int seg = t & 15, el0 = t >> 4;
        const float4 w0 = *(const float4*)(wlast + seg * 8);
        const float4 w1 = *(const float4*)(wlast + seg * 8 + 4);
        const float wl[8] = {w0.x, w0.y, w0.z, w0.w, w1.x, w1.y, w1.z, w1.w};
        f16x8 AV[4], BV[4];
#pragma unroll
        for (int it = 0; it < 4; ++it) {
            const int el = it * 16 + el0;
            AV[it] = *(const f16x8*)(Apre + (size_t)smRow[el] * 128 + seg * 8);
            BV[it] = *(const f16x8*)(Bpre + (size_t)smCol[el] * 128 + seg * 8);
        }
#pragma unroll
        for (int it = 0; it < 4; ++it) {
            const int el = it * 16 + el0;
            const float rd = smRd[el];
            f16x8 vz;
#pragma unroll
            for (int i = 0; i < 8; ++i)
                vz[i] = (f16)fmaxf((float)AV[it][i] + (float)BV[it][i] + rd * wl[i], 0.f);
            *(f16x8*)&smZ[el * S2 + seg * 8] = vz;
        }
    }
    __syncthreads();

    {
        const int p = t & 63, g = t >> 6;
        float a0 = 0.f, a1 = 0.f;
        int prev = smRow[g * 16];
#pragma unroll
        for (int e = g * 16; e < g * 16 + 16; ++e) {
            const int rw = smRow[e];
            if (rw != prev) {
                pk_atomic_add(&zsumh[(size_t)prev * 128 + 2 * p], a0, a1);
                a0 = a1 = 0.f; prev = rw;
            }
            const f16x2 v = *(const f16x2*)&smZ[e * S2 + 2 * p];
            a0 += (float)v[0]; a1 += (float)v[1];
        }
        pk_atomic_add(&zsumh[(size_t)prev * 128 + 2 * p], a0, a1);
    }

    // ---- coord: co = relu(z @ Wx + bx) @ cW2 + cb2 ; scatter rel_pos2*co ----
    f32x4 acc3[4][2] = {};
    for (int kk = 0; kk < 4; ++kk) {
        f16x8 A[4];
#pragma unroll
        for (int rt = 0; rt < 4; ++rt)
            A[rt] = *(const f16x8*)&smZ[(rt * 16 + nn) * S2 + (kk * 4 + qq) * 8];
#pragma unroll
        for (int c = 0; c < 2; ++c) {
            const int ct = w * 2 + c;
            const f16x8 Bh = *(const f16x8*)(Wxs + (size_t)((ct * 4 + kk) * 2) * 512 + lane * 8);
#pragma unroll
            for (int rt = 0; rt < 4; ++rt)
                acc3[rt][c] = __builtin_amdgcn_mfma_f32_16x16x32_f16(A[rt], Bh, acc3[rt][c], 0, 0, 0);
        }
    }
    float p3[4][4];
#pragma unroll
    for (int rt = 0; rt < 4; ++rt)
#pragma unroll
        for (int r = 0; r < 4; ++r) p3[rt][r] = 0.f;
#pragma unroll
    for (int c = 0; c < 2; ++c) {
        const int col = w * 32 + c * 16 + nn;
        const float c1 = bx[col];
        const float w2 = cW2[col];
#pragma unroll
        for (int rt = 0; rt < 4; ++rt)
#pragma unroll
            for (int r = 0; r < 4; ++r)
                p3[rt][r] += fmaxf(acc3[rt][c][r] + c1, 0.f) * w2;
    }
#pragma unroll
    for (int off = 1; off < 16; off <<= 1)
#pragma unroll
        for (int rt = 0; rt < 4; ++rt)
#pragma unroll
            for (int r = 0; r < 4; ++r) p3[rt][r] += __shfl_xor(p3[rt][r], off);
    if (nn == 0) {
#pragma unroll
        for (int rt = 0; rt < 4; ++rt)
#pragma unroll
            for (int r = 0; r < 4; ++r)
                smPart[w][rt * 16 + qq * 4 + r] = p3[rt][r];
    }
    __syncthreads();
    if (t < 64) {
        const float co = smPart[0][t] + smPart[1][t] + smPart[2][t] + smPart[3][t] + cb2[0];
        const int rw = smRow[t];
        atomicAdd(&scat[2 * rw],     smP2x[t] * co);
        atomicAdd(&scat[2 * rw + 1], smP2y[t] * co);
    }
}

// ---- node core: computes h_new, writes h, leaves h_new staged in smA (fragment
// layout, hi/lo split). Shared by both fused kernels. ----
__device__ __forceinline__ void node_core(
    float* __restrict__ h, f16* __restrict__ zsumh,
    const int* __restrict__ deg,
    const f16* __restrict__ nW1cs, const float* __restrict__ nb1,
    const float* __restrict__ bvec,
    const f16* __restrict__ nW2s, const float* __restrict__ nb2,
    f16* smA, float* smDeg, int t, int base)
{
    constexpr int S = 264;
    const int lane = t & 63, w = t >> 6, qq = lane >> 4, nn = lane & 15;

    if (t < 64) smDeg[t] = (float)deg[base + t];   // base+63 <= 50047 < NBINS, safe

    f32x4 acc1[4][2] = {};
    for (int chunk = 0; chunk < 2; ++chunk) {
        if (chunk) __syncthreads();
#pragma unroll
        for (int it = 0; it < 4; ++it) {
            const int idx = it * 256 + t;
            const int el = idx >> 4, seg = idx & 15;
            const int node = base + el;
            f16* dst = &smA[el * S + seg * 16];
            if (node < N_NODES) {
                if (chunk == 0) {
                    stage8(h + (size_t)node * 128 + seg * 8, dst);
                } else {
                    f16* src = zsumh + (size_t)node * 128 + seg * 8;
                    const f16x8 v = *(const f16x8*)src;
                    *(f16x8*)dst = v;                       // hi plane = f16 value
                    *(f16x8*)(dst + 8) = (f16x8)(f16)0.f;   // lo plane = 0
                    *(f16x8*)src = (f16x8)(f16)0.f;         // zero zsumh in place
                }
            } else {
                *(f16x8*)dst = (f16x8)(f16)0.f;
                *(f16x8*)(dst + 8) = (f16x8)(f16)0.f;
            }
        }
        __syncthreads();
        for (int kk = 0; kk < 4; ++kk) {
            f16x8 Ah[4], Al[4];
#pragma unroll
            for (int rt = 0; rt < 4; ++rt) {
                const f16* ap = &smA[(rt * 16 + nn) * S + (kk * 4 + qq) * 16];
                Ah[rt] = *(const f16x8*)ap;
                Al[rt] = *(const f16x8*)(ap + 8);
            }
            const int kkg = chunk * 4 + kk;
#pragma unroll
            for (int c = 0; c < 2; ++c) {
                const int ct = w * 2 + c;
                const f16* bp = nW1cs + (size_t)((ct * 8 + kkg) * 2) * 512 + lane * 8;
                const f16x8 Bh = *(const f16x8*)bp;
                const f16x8 Bl = *(const f16x8*)(bp + 512);
#pragma unroll
                for (int rt = 0; rt < 4; ++rt)
                    acc1[rt][c] = mfma3(Ah[rt], Al[rt], Bh, Bl, acc1[rt][c]);
            }
        }
    }
    __syncthreads();
#pragma unroll
    for (int c = 0; c < 2; ++c) {
        const int col = w * 32 + c * 16 + nn;
        const float b1 = nb1[col];
        const float bv = bvec[col];
#pragma unroll
        for (int rt = 0; rt < 4; ++rt) {
#pragma unroll
            for (int r = 0; r < 4; ++r) {
                const int el = rt * 16 + qq * 4 + r;
                const float z = fmaxf(acc1[rt][c][r] + b1 + smDeg[el] * bv, 0.f);
                f16 zh, zl; split_f(z, zh, zl);
                f16* zp = &smA[el * S + (col >> 3) * 16 + (col & 7)];
                zp[0] = zh; zp[8] = zl;
            }
        }
    }
    __syncthreads();

    f32x4 acc2[4][2] = {};
    for (int kk = 0; kk < 4; ++kk) {
        f16x8 Ah[4], Al[4];
#pragma unroll
        for (int rt = 0; rt < 4; ++rt) {
            const f16* ap = &smA[(rt * 16 + nn) * S + (kk * 4 + qq) * 16];
            Ah[rt] = *(const f16x8*)ap;
            Al[rt] = *(const f16x8*)(ap + 8);
        }
#pragma unroll
        for (int c = 0; c < 2; ++c) {
            const int ct = w * 2 + c;
            const f16* bp = nW2s + (size_t)((ct * 4 + kk) * 2) * 512 + lane * 8;
            const f16x8 Bh = *(const f16x8*)bp;
            const f16x8 Bl = *(const f16x8*)(bp + 512);
#pragma unroll
            for (int rt = 0; rt < 4; ++rt)
                acc2[rt][c] = mfma3(Ah[rt], Al[rt], Bh, Bl, acc2[rt][c]);
        }
    }
    __syncthreads();   // smA z reads done -> overwrite with h_new
#pragma unroll
    for (int c = 0; c < 2; ++c) {
        const int col = w * 32 + c * 16 + nn;
        const float b2 = nb2[col];
#pragma unroll
        for (int rt = 0; rt < 4; ++rt) {
#pragma unroll
            for (int r = 0; r < 4; ++r) {
                const int el = rt * 16 + qq * 4 + r;
                const int node = base + el;
                if (node < N_NODES) {
                    const size_t ix = (size_t)node * 128 + col;
                    const float hn = h[ix] + acc2[rt][c][r] + b2;
                    h[ix] = hn;
                    f16 hh, hl; split_f(hn, hh, hl);
                    f16* hp = &smA[el * S + (col >> 3) * 16 + (col & 7)];
                    hp[0] = hh; hp[8] = hl;
                }
                // node >= N: stale smA rows harmless (outputs guarded by node<N)
            }
        }
    }
    __syncthreads();   // h_new staged for the fused consumer GEMM
}

// ---- node_pre (layer 1): node update fused with pre-GEMM for layer 2 ----
__global__ __launch_bounds__(256, 4) void node_pre_kernel(
    float* __restrict__ h, f16* __restrict__ zsumh,
    const int* __restrict__ deg,
    const f16* __restrict__ nW1cs, const float* __restrict__ nb1,
    const float* __restrict__ bvec,
    const f16* __restrict__ nW2s, const float* __restrict__ nb2,
    const f16* __restrict__ Wpres, const float* __restrict__ eb1,
    f16* __restrict__ Apre, f16* __restrict__ Bpre)
{
    constexpr int S = 264;
    __shared__ f16 smA[64 * S];
    __shared__ float smDeg[64];
    const int t = threadIdx.x;
    const int base = blockIdx.x * 64;
    const int lane = t & 63, w = t >> 6, qq = lane >> 4, nn = lane & 15;

    node_core(h, zsumh, deg, nW1cs, nb1, bvec, nW2s, nb2, smA, smDeg, t, base);

    // pre-GEMM on staged h_new: Apre = h@eW1_top + eb1, Bpre = h@eW1_bot
#pragma unroll
    for (int half = 0; half < 2; ++half) {
        f32x4 acc[4][2] = {};
        for (int kk = 0; kk < 4; ++kk) {
            f16x8 Ah[4], Al[4];
#pragma unroll
            for (int rt = 0; rt < 4; ++rt) {
                const f16* ap = &smA[(rt * 16 + nn) * S + (kk * 4 + qq) * 16];
                Ah[rt] = *(const f16x8*)ap;
                Al[rt] = *(const f16x8*)(ap + 8);
            }
#pragma unroll
            for (int c = 0; c < 2; ++c) {
                const int ct = w * 4 + half * 2 + c;
                const f16* bp = Wpres + (size_t)((ct * 4 + kk) * 2) * 512 + lane * 8;
                const f16x8 Bh = *(const f16x8*)bp;
                const f16x8 Bl = *(const f16x8*)(bp + 512);
#pragma unroll
                for (int rt = 0; rt < 4; ++rt)
                    acc[rt][c] = mfma3(Ah[rt], Al[rt], Bh, Bl, acc[rt][c]);
            }
        }
#pragma unroll
        for (int c = 0; c < 2; ++c) {
            const int col = w * 64 + half * 32 + c * 16 + nn;   // 0..255
#pragma unroll
            for (int rt = 0; rt < 4; ++rt) {
#pragma unroll
                for (int r = 0; r < 4; ++r) {
                    const int el = rt * 16 + qq * 4 + r;
                    const int node = base + el;
                    if (node < N_NODES) {
                        const float v = acc[rt][c][r];
                        if (col < 128) Apre[(size_t)node * 128 + col] = (f16)(v + eb1[col]);
                        else           Bpre[(size_t)node * 128 + (col - 128)] = (f16)v;
                    }
                }
            }
        }
    }
}

// ---- node_final (layer 2): node update fused with v-MLP + normalize + x copy ----
__global__ __launch_bounds__(256, 4) void node_final_kernel(
    float* __restrict__ h, f16* __restrict__ zsumh,
    const int* __restrict__ deg,
    const f16* __restrict__ nW1cs, const float* __restrict__ nb1,
    const float* __restrict__ bvec,
    const f16* __restrict__ nW2s, const float* __restrict__ nb2,
    const f16* __restrict__ vW1s, const float* __restrict__ vb1,
    const float* __restrict__ vW2, const float* __restrict__ vb2,
    const float* __restrict__ scat, const float* __restrict__ x,
    float* __restrict__ out)
{
    constexpr int S = 264;
    __shared__ f16 smA[64 * S];
    __shared__ float smDeg[64];
    const int t = threadIdx.x;
    const int base = blockIdx.x * 64;
    const int lane = t & 63, w = t >> 6, qq = lane >> 4, nn = lane & 15;

    node_core(h, zsumh, deg, nW1cs, nb1, bvec, nW2s, nb2, smA, smDeg, t, base);

    // v-GEMM on staged h_new: z = relu(h@vW1 + vb1) -> smA
    f32x4 acc1[4][2] = {};
    for (int kk = 0; kk < 4; ++kk) {
        f16x8 Ah[4], Al[4];
#pragma unroll
        for (int rt = 0; rt < 4; ++rt) {
            const f16* ap = &smA[(rt * 16 + nn) * S + (kk * 4 + qq) * 16];
            Ah[rt] = *(const f16x8*)ap;
            Al[rt] = *(const f16x8*)(ap + 8);
        }
#pragma unroll
        for (int c = 0; c < 2; ++c) {
            const int ct = w * 2 + c;
            const f16* bp = vW1s + (size_t)((ct * 4 + kk) * 2) * 512 + lane * 8;
            const f16x8 Bh = *(const f16x8*)bp;
            const f16x8 Bl = *(const f16x8*)(bp + 512);
#pragma unroll
            for (int rt = 0; rt < 4; ++rt)
                acc1[rt][c] = mfma3(Ah[rt], Al[rt], Bh, Bl, acc1[rt][c]);
        }
    }
    __syncthreads();
#pragma unroll
    for (int c = 0; c < 2; ++c) {
        const int col = w * 32 + c * 16 + nn;
        const float b1 = vb1[col];
#pragma unroll
        for (int rt = 0; rt < 4; ++rt) {
#pragma unroll
            for (int r = 0; r < 4; ++r) {
                const int el = rt * 16 + qq * 4 + r;
                const float z = fmaxf(acc1[rt][c][r] + b1, 0.f);
                f16 zh, zl; split_f(z, zh, zl);
                f16* zp = &smA[el * S + (col >> 3) * 16 + (col & 7)];
                zp[0] = zh; zp[8] = zl;
            }
        }
    }
    __syncthreads();

    float* out_x = out + (size_t)N_NODES * 128;
    float* out_v = out_x + (size_t)N_NODES * 2;
    if (t < 128) {
        const int node = base + (t >> 1);
        if (node < N_NODES) out_x[node * 2 + (t & 1)] = x[node * 2 + (t & 1)];
    }
    if (t < 128) {
        const int rl = t >> 1, comp = t & 1;
        const int node = base + rl;
        float s = 0.f;
        if (node < N_NODES) {
            s = vb2[comp];
            for (int k = 0; k < 128; ++k) {
                const f16* zp = &smA[rl * S + (k >> 3) * 16 + (k & 7)];
                const float z = (float)zp[0] + (float)zp[8];
                s += z * vW2[k * 2 + comp];
            }
            const float dn = fmaxf((float)smDeg[rl], 1.0f);
            s += scat[node * 2 + comp] / dn;
        }
        const float other = __shfl_xor(s, 1);
        if (node < N_NODES) {
            const float nrm = sqrtf(s * s + other * other);
            out_v[node * 2 + comp] = s / fmaxf(nrm, 1e-12f);
        }
    }
}

extern "C" void kernel_launch(void* const* d_in, const int* in_sizes, int n_in,
                              void* d_out, int out_size, void* d_ws, size_t ws_size,
                              hipStream_t stream) {
    const float* h_in = (const float*)d_in[0];
    const float* x    = (const float*)d_in[1];
    const int*   eidx = (const int*)d_in[2];
    const float* embW = (const float*)d_in[3];
    const float* embb = (const float*)d_in[4];
    const float* eW1  = (const float*)d_in[5];
    const float* eb1  = (const float*)d_in[6];
    const float* eW2  = (const float*)d_in[7];
    const float* eb2  = (const float*)d_in[8];
    const float* nW1  = (const float*)d_in[9];
    const float* nb1  = (const float*)d_in[10];
    const float* nW2  = (const float*)d_in[11];
    const float* nb2  = (const float*)d_in[12];
    const float* vW1  = (const float*)d_in[13];
    const float* vb1  = (const float*)d_in[14];
    const float* vW2  = (const float*)d_in[15];
    const float* vb2  = (const float*)d_in[16];
    const float* cW1  = (const float*)d_in[17];
    const float* cb1  = (const float*)d_in[18];
    const float* cW2  = (const float*)d_in[19];
    const float* cb2  = (const float*)d_in[20];

    char* ws = (char*)d_ws;
    int* deg    = (int*)(ws + OFF_DEG);
    int* locEx  = (int*)(ws + OFF_LOCEX);
    int* bsum   = (int*)(ws + OFF_BSUM);
    int* boff   = (int*)(ws + OFF_BOFF);
    int* fill   = (int*)(ws + OFF_FILL);
    float* scat = (float*)(ws + OFF_SCAT);
    u32* sedge  = (u32*)(ws + OFF_SEDGE);
    f16* zsumh  = (f16*)(ws + OFF_ZSUM);
    f16* Apre   = (f16*)(ws + OFF_APRE);
    f16* Bpre   = (f16*)(ws + OFF_BPRE);
    float* Wcmb = (float*)(ws + OFF_CMB);
    float* Wx   = (float*)(ws + OFF_WX);
    float* bvec = (float*)(ws + OFF_BVEC);
    float* bx   = (float*)(ws + OFF_BX);
    f16* Wpres  = (f16*)(ws + OFF_WSWZ);
    f16* nW1cs  = Wpres + 65536;
    f16* nW2s   = nW1cs + 65536;
    f16* vW1s   = nW2s + 32768;
    f16* Wxs    = vW1s + 32768;

    // h lives in d_out's h-region: final copy is free
    float* hcur = (float*)d_out;

    // zero deg/locEx/bsum/boff/fill/scat (1 MB) + zsumh (12.8 MB; node kernels
    // re-zero zsumh in-place every call thereafter)
    hipMemsetAsync(ws, 0, OFF_SEDGE, stream);
    hipMemsetAsync(zsumh, 0, ZSH_BYTES, stream);

    compose_kernel<<<129, 256, 0, stream>>>(eW2, eb2, nW1, cW1, cb1, Wcmb, Wx, bvec, bx);
    prep_kernel<<<448, 256, 0, stream>>>(eW1, nW1, nW2, vW1, Wcmb, Wx,
                                         Wpres, nW1cs, nW2s, vW1s, Wxs);
    hist_kernel<<<(E_EDGES + 255) / 256, 256, 0, stream>>>(eidx, deg);
    scan1_kernel<<<NBLK, 256, 0, stream>>>(deg, locEx, bsum);
    scan2_kernel<<<1, 256, 0, stream>>>(bsum, boff);
    scatter_kernel<<<(E_EDGES + 255) / 256, 256, 0, stream>>>(eidx, locEx, boff,
                                                              fill, sedge);
    embed_kernel<<<(N_NODES * 128 + 255) / 256, 256, 0, stream>>>(h_in, embW, embb, hcur);

    const float* wlast = eW1 + 256 * 128;   // rel_dist row of eW1

    // layer 1
    pre_kernel<<<(N_NODES + 63) / 64, 256, 0, stream>>>(hcur, Wpres, eb1, Apre, Bpre);
    edge_z_kernel<<<E_EDGES / 64, 256, 0, stream>>>(sedge, x, Apre, Bpre, wlast, zsumh);
    node_pre_kernel<<<(N_NODES + 63) / 64, 256, 0, stream>>>(hcur, zsumh, deg,
        nW1cs, nb1, bvec, nW2s, nb2, Wpres, eb1, Apre, Bpre);

    // layer 2 (with coord + scatter); zsumh zeroed in-place by node_pre
    edge_coord_kernel<<<E_EDGES / 64, 256, 0, stream>>>(sedge, x, Apre, Bpre, wlast,
        Wxs, bx, cW2, cb2, zsumh, scat);
    node_final_kernel<<<(N_NODES + 63) / 64, 256, 0, stream>>>(hcur, zsumh, deg,
        nW1cs, nb1, bvec, nW2s, nb2, vW1s, vb1, vW2, vb2, scat, x, (float*)d_out);
}